// Round 7
// baseline (750.305 us; speedup 1.0000x reference)
//
#include <hip/hip_runtime.h>
#include <hip/hip_bf16.h>

static constexpr int NN      = 50000;
static constexpr int FIN     = 1433;
static constexpr int KPAD    = 1440;            // 45 * 32
static constexpr int NB_SCAN = (NN + 255) / 256; // 196
static constexpr int GB1     = (NN + 63) / 64;   // 782 gemm1 tiles

typedef __bf16 bf16x8 __attribute__((ext_vector_type(8)));
typedef float  f32x4  __attribute__((ext_vector_type(4)));

__device__ __forceinline__ float leaky02(float v){ return v >= 0.f ? v : 0.2f * v; }

// async global->LDS, 4 bytes/lane: lane l writes lds_base + l*4
__device__ __forceinline__ void gld_lds4(const float* g, float* l){
    __builtin_amdgcn_global_load_lds(
        (const __attribute__((address_space(1))) unsigned int*)g,
        (__attribute__((address_space(3))) unsigned int*)l, 4, 0, 0);
}

// ---------------- prep: W1 transpose/split + deg zero, one dispatch ----------------
__global__ __launch_bounds__(256) void k_prep(const float* __restrict__ W1,
                                              __bf16* __restrict__ w1h, __bf16* __restrict__ w1l,
                                              int* __restrict__ deg){
    int bid = blockIdx.x;
    if (bid < 64){
        int c = bid;                          // output column
        for (int k = threadIdx.x; k < KPAD; k += 256){
            float v = (k < FIN) ? W1[(size_t)k * 64 + c] : 0.f;
            __bf16 hi = (__bf16)v;
            w1h[(size_t)c * KPAD + k] = hi;
            w1l[(size_t)c * KPAD + k] = (__bf16)(v - (float)hi);
        }
    } else {
        int i = (bid - 64) * 256 + threadIdx.x;
        if (i < NN) deg[i] = 0;
    }
}

// ---------------- CSR scans ----------------
__global__ __launch_bounds__(256) void k_scan1(const int* __restrict__ deg, int* __restrict__ bsum){
    __shared__ int red[256];
    int i = blockIdx.x * 256 + threadIdx.x;
    red[threadIdx.x] = (i < NN) ? deg[i] : 0;
    __syncthreads();
    for (int off = 128; off > 0; off >>= 1){
        if (threadIdx.x < off) red[threadIdx.x] += red[threadIdx.x + off];
        __syncthreads();
    }
    if (threadIdx.x == 0) bsum[blockIdx.x] = red[0];
}

__global__ __launch_bounds__(256) void k_scan2(const int* __restrict__ bsum, int* __restrict__ bofs){
    __shared__ int s[256];
    int t = threadIdx.x;
    s[t] = (t < NB_SCAN) ? bsum[t] : 0;
    __syncthreads();
    for (int off = 1; off < 256; off <<= 1){
        int v = s[t];
        int a = (t >= off) ? s[t - off] : 0;
        __syncthreads();
        s[t] = v + a;
        __syncthreads();
    }
    if (t < NB_SCAN) bofs[t] = (t > 0) ? s[t - 1] : 0;
}

__global__ __launch_bounds__(256) void k_scan3(const int* __restrict__ deg, const int* __restrict__ bofs,
                                               int* __restrict__ row_off){
    __shared__ int s[256];
    int t = threadIdx.x;
    int i = blockIdx.x * 256 + t;
    int d = (i < NN) ? deg[i] : 0;
    s[t] = d;
    __syncthreads();
    for (int off = 1; off < 256; off <<= 1){
        int v = s[t];
        int a = (t >= off) ? s[t - off] : 0;
        __syncthreads();
        s[t] = v + a;
        __syncthreads();
    }
    int excl = s[t] - d + bofs[blockIdx.x];
    if (i < NN){
        row_off[i] = excl;
        if (i == NN - 1) row_off[NN] = excl + d;
    }
}

// atomic-free scatter using precomputed rank
__global__ __launch_bounds__(256) void k_scatter(const int* __restrict__ src, const int* __restrict__ dst,
                                                 const int* __restrict__ rank, const int* __restrict__ row_off,
                                                 int* __restrict__ csr, int E){
    int e = blockIdx.x * 256 + threadIdx.x;
    if (e < E) csr[row_off[dst[e]] + rank[e]] = src[e];
}

// ---------------- fused GEMM1 (+alpha1) and edge-rank histogram ----------------
// Block role by bid: bid%8==0 -> gemm1 tile (bid>>3), else rank chunk.
// GEMM1: 64 rows/block, 4 waves; wave w owns cols w*16..w*16+15. A staged f32 via
// global_load_lds, double-buffered K=64 blocks, LDS row stride 68 floats.
// Outputs: Hb0/Hb1 [N][32] bf16, asadA/asadB [N][8] bf16 ([0..3]=as,[4..7]=ad).
__global__ __launch_bounds__(256, 3) void k_g1r(const float* __restrict__ x,
    const __bf16* __restrict__ w1h, const __bf16* __restrict__ w1l,
    const float* __restrict__ a_s, const float* __restrict__ a_d,
    __bf16* __restrict__ Hb0, __bf16* __restrict__ Hb1,
    __bf16* __restrict__ asadA, __bf16* __restrict__ asadB,
    const int* __restrict__ dst, int* __restrict__ deg, int* __restrict__ rank, int E)
{
    __shared__ float As[2 * 64 * 68];        // 34.8 KB
    const int bid = blockIdx.x;
    const int tid = threadIdx.x;

    if ((bid & 7) != 0){                     // ---- rank role ----
        int ridx = bid - (bid >> 3) - 1;
        int e = ridx * 256 + tid;
        if (e < E) rank[e] = atomicAdd(&deg[dst[e]], 1);
        return;
    }
    const int gidx = bid >> 3;               // ---- gemm1 role ----
    if (gidx >= GB1) return;

    const int w    = tid >> 6;
    const int lane = tid & 63;
    const int lr   = lane & 15;
    const int lk   = lane >> 4;
    const int rbase = gidx * 64;

    unsigned rowoff[16];
    #pragma unroll
    for (int i = 0; i < 16; ++i){
        int rg = rbase + w * 16 + i; if (rg >= NN) rg = NN - 1;
        rowoff[i] = (unsigned)rg * (unsigned)FIN + (unsigned)lane;
    }

    const __bf16* bh_p = w1h + (size_t)(w * 16 + lr) * KPAD + lk * 8;
    const __bf16* bl_p = w1l + (size_t)(w * 16 + lr) * KPAD + lk * 8;

    f32x4 acc[4] = {{0,0,0,0},{0,0,0,0},{0,0,0,0},{0,0,0,0}};

    #pragma unroll
    for (int i = 0; i < 16; ++i)
        gld_lds4(x + rowoff[i], &As[(w * 16 + i) * 68]);
    __syncthreads();

    for (int kb = 0; kb < 22; ++kb){
        const int cur = kb & 1;
        if (kb < 21){
            const float* gsrc = x + (kb + 1) * 64;
            float* lb = &As[(1 - cur) * 4352];
            #pragma unroll
            for (int i = 0; i < 16; ++i)
                gld_lds4(gsrc + rowoff[i], lb + (w * 16 + i) * 68);
        }
        const int kA = kb * 64;
        bf16x8 bh0 = *(const bf16x8*)(bh_p + kA);
        bf16x8 bl0 = *(const bf16x8*)(bl_p + kA);
        bf16x8 bh1 = *(const bf16x8*)(bh_p + kA + 32);
        bf16x8 bl1 = *(const bf16x8*)(bl_p + kA + 32);
        const float* ab = &As[cur * 4352] + lk * 8;
        #pragma unroll
        for (int ks = 0; ks < 2; ++ks){
            bf16x8 bh = ks ? bh1 : bh0;
            bf16x8 bl = ks ? bl1 : bl0;
            #pragma unroll
            for (int t = 0; t < 4; ++t){
                const float* p = ab + (t * 16 + lr) * 68 + ks * 32;
                f32x4 v0 = *(const f32x4*)p;
                f32x4 v1 = *(const f32x4*)(p + 4);
                bf16x8 ah, al;
                #pragma unroll
                for (int e = 0; e < 4; ++e){
                    __bf16 h0 = (__bf16)v0[e];
                    ah[e]     = h0; al[e]     = (__bf16)(v0[e] - (float)h0);
                    __bf16 h1 = (__bf16)v1[e];
                    ah[e + 4] = h1; al[e + 4] = (__bf16)(v1[e] - (float)h1);
                }
                acc[t] = __builtin_amdgcn_mfma_f32_16x16x32_bf16(ah, bh, acc[t], 0, 0, 0);
                acc[t] = __builtin_amdgcn_mfma_f32_16x16x32_bf16(al, bh, acc[t], 0, 0, 0);
                acc[t] = __builtin_amdgcn_mfma_f32_16x16x32_bf16(ah, bl, acc[t], 0, 0, 0);
            }
        }
        __syncthreads();
    }

    // peeled masked tail: k 1408..1439 (valid < 1433)
    {
        bf16x8 bh = *(const bf16x8*)(bh_p + 1408);
        bf16x8 bl = *(const bf16x8*)(bl_p + 1408);
        #pragma unroll
        for (int t = 0; t < 4; ++t){
            int rg = rbase + t * 16 + lr; if (rg >= NN) rg = NN - 1;
            const float* xr = x + (size_t)rg * FIN;
            bf16x8 ah, al;
            #pragma unroll
            for (int e = 0; e < 8; ++e){
                int k = 1408 + lk * 8 + e;
                float v = (k < FIN) ? xr[k] : 0.f;
                __bf16 h = (__bf16)v;
                ah[e] = h; al[e] = (__bf16)(v - (float)h);
            }
            acc[t] = __builtin_amdgcn_mfma_f32_16x16x32_bf16(ah, bh, acc[t], 0, 0, 0);
            acc[t] = __builtin_amdgcn_mfma_f32_16x16x32_bf16(al, bh, acc[t], 0, 0, 0);
            acc[t] = __builtin_amdgcn_mfma_f32_16x16x32_bf16(ah, bl, acc[t], 0, 0, 0);
        }
    }

    // epilogue 1: H tile -> LDS + bf16 head-half stores
    __syncthreads();
    const int col = w * 16 + lr;
    __bf16* hbp = (col < 32) ? Hb0 : Hb1;
    const int cc = col & 31;
    #pragma unroll
    for (int t = 0; t < 4; ++t){
        #pragma unroll
        for (int r = 0; r < 4; ++r){
            int rib = t * 16 + lk * 4 + r;
            float v = acc[t][r];
            As[rib * 68 + col] = v;
            int row = rbase + rib;
            if (row < NN) hbp[(size_t)row * 32 + cc] = (__bf16)v;
        }
    }
    __syncthreads();
    // epilogue 2: fused alpha1 -> bf16 asad records
    #pragma unroll
    for (int it = 0; it < 2; ++it){
        int task = tid + it * 256;
        int row  = task >> 3;
        int hh   = task & 7;
        int grow = rbase + row;
        if (grow < NN){
            const float* hr = &As[row * 68 + hh * 8];
            float s = 0.f, dd = 0.f;
            #pragma unroll
            for (int c = 0; c < 8; ++c){
                float v = hr[c];
                s  = fmaf(v, a_s[hh * 8 + c], s);
                dd = fmaf(v, a_d[hh * 8 + c], dd);
            }
            if (hh < 4){
                asadA[(size_t)grow * 8 + hh]     = (__bf16)s;
                asadA[(size_t)grow * 8 + 4 + hh] = (__bf16)dd;
            } else {
                asadB[(size_t)grow * 8 + (hh - 4)]     = (__bf16)s;
                asadB[(size_t)grow * 8 + 4 + (hh - 4)] = (__bf16)dd;
            }
        }
    }
}

// ---------------- layer-1 edge pass, one head-half per dispatch ----------------
// wave = 1 dst node; lane = (edge slot e2 = lane>>5) x (channel c = lane&31).
// Random WS per pass: HbP 3.2MB + asadP 0.8MB -> ~per-XCD L2.
__global__ __launch_bounds__(256, 6) void k_layer1p(const __bf16* __restrict__ asadP,
    const __bf16* __restrict__ HbP, const int* __restrict__ row_off, const int* __restrict__ csr,
    const float* __restrict__ b1P, float* __restrict__ x2, int colbase)
{
    const int d    = blockIdx.x * 4 + (threadIdx.x >> 6);
    const int lane = threadIdx.x & 63;
    const int e2   = lane >> 5;
    const int c    = lane & 31;
    const int h    = c >> 3;
    const float adv = (float)asadP[(size_t)d * 8 + 4 + h];
    float den, acc;
    {
        float as_d = (float)asadP[(size_t)d * 8 + h];
        float e0 = leaky02(as_d + adv);
        float p0 = __expf(e0 - 20.f);            // fixed-offset softmax (e bounded << 20)
        den = e2 ? 0.f : p0;
        acc = e2 ? 0.f : p0 * (float)HbP[(size_t)d * 32 + c];
    }
    const int beg = row_off[d], end = row_off[d + 1];
    const int nfull = (end - beg) >> 4;
    const int* cp = csr + beg + e2;

    float pa[8], hb[8];
    if (nfull > 0){
        #pragma unroll
        for (int t = 0; t < 8; ++t){
            int s = __builtin_nontemporal_load(cp + 2 * t);
            pa[t] = (float)asadP[(size_t)s * 8 + h];
            hb[t] = (float)HbP[(size_t)s * 32 + c];
        }
        for (int b = 1; b < nfull; ++b){
            float npa[8], nhb[8];
            const int* cpb = cp + b * 16;
            #pragma unroll
            for (int t = 0; t < 8; ++t){
                int s = __builtin_nontemporal_load(cpb + 2 * t);
                npa[t] = (float)asadP[(size_t)s * 8 + h];
                nhb[t] = (float)HbP[(size_t)s * 32 + c];
            }
            #pragma unroll
            for (int t = 0; t < 8; ++t){
                float e = leaky02(pa[t] + adv);
                float p = __expf(e - 20.f);
                den += p; acc = fmaf(p, hb[t], acc);
            }
            #pragma unroll
            for (int t = 0; t < 8; ++t){ pa[t] = npa[t]; hb[t] = nhb[t]; }
        }
        #pragma unroll
        for (int t = 0; t < 8; ++t){
            float e = leaky02(pa[t] + adv);
            float p = __expf(e - 20.f);
            den += p; acc = fmaf(p, hb[t], acc);
        }
    }
    {   // tail (0..15 edges), masked
        int tb = beg + nfull * 16;
        int tc = end - tb;
        if (tc > 0){
            #pragma unroll
            for (int t = 0; t < 8; ++t){
                int j = 2 * t + e2;
                int idx = tb + (j < tc ? j : tc - 1);
                int s = __builtin_nontemporal_load(csr + idx);
                float pav = (float)asadP[(size_t)s * 8 + h];
                float hbv = (float)HbP[(size_t)s * 32 + c];
                if (j < tc){
                    float e = leaky02(pav + adv);
                    float p = __expf(e - 20.f);
                    den += p; acc = fmaf(p, hbv, acc);
                }
            }
        }
    }
    acc += __shfl_xor(acc, 32, 64);
    den += __shfl_xor(den, 32, 64);
    if (e2 == 0){
        float o = acc / den + b1P[c];
        x2[(size_t)d * 64 + colbase + c] = (o > 0.f) ? o : (__expf(o) - 1.f);   // ELU fused
    }
}

// ---------------- GEMM2 + attention logits, layer 2 ----------------
// h2a[n][8]: [0..6] = h2 channels, [7] = as2 (packed record, one gather/edge later)
__global__ __launch_bounds__(256) void k_gemm2(const float* __restrict__ x2, const float* __restrict__ W2,
    const float* __restrict__ aw_in, const float* __restrict__ dw_in,
    float* __restrict__ h2a, float* __restrict__ ad2)
{
    __shared__ float w2s[448];
    __shared__ float aw[7], dw[7];
    int tid = threadIdx.x;
    for (int i = tid; i < 448; i += 256) w2s[i] = W2[i];
    if (tid < 7){ aw[tid] = aw_in[tid]; dw[tid] = dw_in[tid]; }
    __syncthreads();
    int n = blockIdx.x * 256 + tid;
    if (n >= NN) return;
    const float4* xp = (const float4*)(x2 + (size_t)n * 64);
    float acc[7] = {0.f,0.f,0.f,0.f,0.f,0.f,0.f};
    #pragma unroll
    for (int q = 0; q < 16; ++q){
        float4 v = xp[q];
        float vv[4] = {v.x, v.y, v.z, v.w};
        #pragma unroll
        for (int u = 0; u < 4; ++u){
            int k = q * 4 + u;
            #pragma unroll
            for (int c = 0; c < 7; ++c) acc[c] = fmaf(vv[u], w2s[k * 7 + c], acc[c]);
        }
    }
    float s = 0.f, d = 0.f;
    #pragma unroll
    for (int c = 0; c < 7; ++c){ s = fmaf(acc[c], aw[c], s); d = fmaf(acc[c], dw[c], d); }
    float* hp = h2a + (size_t)n * 8;
    #pragma unroll
    for (int c = 0; c < 7; ++c) hp[c] = acc[c];
    hp[7] = s;                                  // as2 packed into the record
    ad2[n] = d;
}

// ---------------- layer-2 edge pass + bias + log_softmax: 8 lanes/node, 16-edge batches ----------------
__global__ __launch_bounds__(256) void k_layer2(const float* __restrict__ ad2,
    const float* __restrict__ h2a, const int* __restrict__ row_off, const int* __restrict__ csr,
    const float* __restrict__ b2, float* __restrict__ out)
{
    int tid  = threadIdx.x;
    int node = blockIdx.x * 32 + (tid >> 3);
    int c    = tid & 7;
    int lane = tid & 63;
    int gb   = lane & ~7;                        // 8-lane group base within wave
    if (node >= NN) return;
    float adv   = ad2[node];
    float vself = h2a[(size_t)node * 8 + c];
    float as_n  = __shfl(vself, gb + 7, 64);
    float e0 = leaky02(as_n + adv);
    float p0 = __expf(e0 - 20.f);
    float den = p0;
    float acc = p0 * vself;                      // c==7 lane accumulates garbage; unused
    int beg = row_off[node], end = row_off[node + 1];
    for (int base = beg; base < end; base += 16){
        int cnt = end - base; if (cnt > 16) cnt = 16;
        int j1  = 8 + c;
        int cs0 = csr[base + (c  < cnt ? c  : cnt - 1)];
        int cs1 = csr[base + (j1 < cnt ? j1 : cnt - 1)];
        float val[16];
        #pragma unroll
        for (int t = 0; t < 16; ++t){
            if (t < cnt){
                int s = (t < 8) ? __shfl(cs0, gb + t, 64) : __shfl(cs1, gb + t - 8, 64);
                val[t] = h2a[(size_t)s * 8 + c];
            }
        }
        #pragma unroll
        for (int t = 0; t < 16; ++t){
            if (t < cnt){
                float as_s = __shfl(val[t], gb + 7, 64);
                float e = leaky02(as_s + adv);
                float p = __expf(e - 20.f);
                den += p;
                acc  = fmaf(p, val[t], acc);
            }
        }
    }
    float v = (c < 7) ? (acc / den + b2[c]) : -1e30f;
    float m = v;
    m = fmaxf(m, __shfl_xor(m, 1, 64));
    m = fmaxf(m, __shfl_xor(m, 2, 64));
    m = fmaxf(m, __shfl_xor(m, 4, 64));
    float ex = (c < 7) ? __expf(v - m) : 0.f;
    float s7 = ex;
    s7 += __shfl_xor(s7, 1, 64);
    s7 += __shfl_xor(s7, 2, 64);
    s7 += __shfl_xor(s7, 4, 64);
    if (c < 7) out[(size_t)node * 7 + c] = v - m - __logf(s7);
}

// ---------------- launcher ----------------
extern "C" void kernel_launch(void* const* d_in, const int* in_sizes, int n_in,
                              void* d_out, int out_size, void* d_ws, size_t ws_size,
                              hipStream_t stream)
{
    (void)n_in; (void)out_size; (void)ws_size;
    const float* x      = (const float*)d_in[0];
    const int*   ei     = (const int*)d_in[1];
    const int    E      = in_sizes[1] / 2;
    const float* W1     = (const float*)d_in[2];
    const float* asrc1  = (const float*)d_in[3];
    const float* adst1  = (const float*)d_in[4];
    const float* b1     = (const float*)d_in[5];
    const float* W2     = (const float*)d_in[6];
    const float* asrc2  = (const float*)d_in[7];
    const float* adst2  = (const float*)d_in[8];
    const float* b2     = (const float*)d_in[9];
    float* out = (float*)d_out;

    char* p = (char*)d_ws;
    auto alloc = [&](size_t bytes) -> void* {
        void* r = (void*)p;
        p += (bytes + 255) & ~(size_t)255;
        return r;
    };
    int*    deg     = (int*)alloc((size_t)NN * 4);
    int*    row_off = (int*)alloc((size_t)(NN + 1) * 4);
    int*    rank    = (int*)alloc((size_t)E * 4);
    int*    bsum    = (int*)alloc((size_t)NB_SCAN * 4);
    int*    bofs    = (int*)alloc((size_t)NB_SCAN * 4);
    int*    csr     = (int*)alloc((size_t)E * 4);
    __bf16* w1h     = (__bf16*)alloc((size_t)64 * KPAD * 2);
    __bf16* w1l     = (__bf16*)alloc((size_t)64 * KPAD * 2);
    __bf16* Hb0     = (__bf16*)alloc((size_t)NN * 32 * 2);
    __bf16* Hb1     = (__bf16*)alloc((size_t)NN * 32 * 2);
    __bf16* asadA   = (__bf16*)alloc((size_t)NN * 8 * 2);
    __bf16* asadB   = (__bf16*)alloc((size_t)NN * 8 * 2);
    float*  x2      = (float*)alloc((size_t)NN * 64 * 4);
    float*  h2a     = (float*)alloc((size_t)NN * 8 * 4);
    float*  ad2     = (float*)alloc((size_t)NN * 4);

    const int* src = ei;
    const int* dst = ei + E;

    const int RB = (E + 255) / 256;
    int T = ((RB + 6) / 7) * 8;               // rank slots = T - ceil(T/8) >= RB
    if (T < GB1 * 8) T = GB1 * 8;             // gemm slots = ceil(T/8) >= GB1

    k_prep   <<<64 + NB_SCAN, 256, 0, stream>>>(W1, w1h, w1l, deg);
    k_g1r    <<<T, 256, 0, stream>>>(x, w1h, w1l, asrc1, adst1,
                                     Hb0, Hb1, asadA, asadB, dst, deg, rank, E);
    k_scan1  <<<NB_SCAN, 256, 0, stream>>>(deg, bsum);
    k_scan2  <<<1, 256, 0, stream>>>(bsum, bofs);
    k_scan3  <<<NB_SCAN, 256, 0, stream>>>(deg, bofs, row_off);
    k_scatter<<<(E + 255) / 256, 256, 0, stream>>>(src, dst, rank, row_off, csr, E);
    k_layer1p<<<NN / 4, 256, 0, stream>>>(asadA, Hb0, row_off, csr, b1,      x2, 0);
    k_layer1p<<<NN / 4, 256, 0, stream>>>(asadB, Hb1, row_off, csr, b1 + 32, x2, 32);
    k_gemm2  <<<(NN + 255) / 256, 256, 0, stream>>>(x2, W2, asrc2, adst2, h2a, ad2);
    k_layer2 <<<(NN + 31) / 32, 256, 0, stream>>>(ad2, h2a, row_off, csr, b2, out);
}

// Round 8
// 366.621 us; speedup vs baseline: 2.0465x; 2.0465x over previous
//
#include <hip/hip_runtime.h>
#include <hip/hip_bf16.h>

static constexpr int NN      = 50000;
static constexpr int FIN     = 1433;
static constexpr int KPAD    = 1440;            // 45 * 32
static constexpr int NB_SCAN = (NN + 255) / 256; // 196

typedef __bf16 bf16x8 __attribute__((ext_vector_type(8)));
typedef float  f32x4  __attribute__((ext_vector_type(4)));

__device__ __forceinline__ float leaky02(float v){ return v >= 0.f ? v : 0.2f * v; }

// async global->LDS, 4 bytes/lane: lane l writes lds_base + l*4
__device__ __forceinline__ void gld_lds4(const float* g, float* l){
    __builtin_amdgcn_global_load_lds(
        (const __attribute__((address_space(1))) unsigned int*)g,
        (__attribute__((address_space(3))) unsigned int*)l, 4, 0, 0);
}

// ---------------- prep: W1 transpose/split + deg zero, one dispatch ----------------
__global__ __launch_bounds__(256) void k_prep(const float* __restrict__ W1,
                                              __bf16* __restrict__ w1h, __bf16* __restrict__ w1l,
                                              int* __restrict__ deg){
    int bid = blockIdx.x;
    if (bid < 64){
        int c = bid;                          // output column
        for (int k = threadIdx.x; k < KPAD; k += 256){
            float v = (k < FIN) ? W1[(size_t)k * 64 + c] : 0.f;
            __bf16 hi = (__bf16)v;
            w1h[(size_t)c * KPAD + k] = hi;
            w1l[(size_t)c * KPAD + k] = (__bf16)(v - (float)hi);
        }
    } else {
        int i = (bid - 64) * 256 + threadIdx.x;
        if (i < NN) deg[i] = 0;
    }
}

// ---------------- CSR build ----------------
// hist + per-edge rank in ONE atomic pass (separate kernel: do NOT fuse with gemm1,
// r7 showed fused regalloc spills the MFMA working set)
__global__ __launch_bounds__(256) void k_rank(const int* __restrict__ dst, int* __restrict__ deg,
                                              int* __restrict__ rank, int E){
    int e = blockIdx.x * 256 + threadIdx.x;
    if (e < E) rank[e] = atomicAdd(&deg[dst[e]], 1);
}

__global__ __launch_bounds__(256) void k_scan1(const int* __restrict__ deg, int* __restrict__ bsum){
    __shared__ int red[256];
    int i = blockIdx.x * 256 + threadIdx.x;
    red[threadIdx.x] = (i < NN) ? deg[i] : 0;
    __syncthreads();
    for (int off = 128; off > 0; off >>= 1){
        if (threadIdx.x < off) red[threadIdx.x] += red[threadIdx.x + off];
        __syncthreads();
    }
    if (threadIdx.x == 0) bsum[blockIdx.x] = red[0];
}

__global__ __launch_bounds__(256) void k_scan2(const int* __restrict__ bsum, int* __restrict__ bofs){
    __shared__ int s[256];
    int t = threadIdx.x;
    s[t] = (t < NB_SCAN) ? bsum[t] : 0;
    __syncthreads();
    for (int off = 1; off < 256; off <<= 1){
        int v = s[t];
        int a = (t >= off) ? s[t - off] : 0;
        __syncthreads();
        s[t] = v + a;
        __syncthreads();
    }
    if (t < NB_SCAN) bofs[t] = (t > 0) ? s[t - 1] : 0;
}

__global__ __launch_bounds__(256) void k_scan3(const int* __restrict__ deg, const int* __restrict__ bofs,
                                               int* __restrict__ row_off){
    __shared__ int s[256];
    int t = threadIdx.x;
    int i = blockIdx.x * 256 + t;
    int d = (i < NN) ? deg[i] : 0;
    s[t] = d;
    __syncthreads();
    for (int off = 1; off < 256; off <<= 1){
        int v = s[t];
        int a = (t >= off) ? s[t - off] : 0;
        __syncthreads();
        s[t] = v + a;
        __syncthreads();
    }
    int excl = s[t] - d + bofs[blockIdx.x];
    if (i < NN){
        row_off[i] = excl;
        if (i == NN - 1) row_off[NN] = excl + d;
    }
}

// atomic-free scatter using precomputed rank
__global__ __launch_bounds__(256) void k_scatter(const int* __restrict__ src, const int* __restrict__ dst,
                                                 const int* __restrict__ rank, const int* __restrict__ row_off,
                                                 int* __restrict__ csr, int E){
    int e = blockIdx.x * 256 + threadIdx.x;
    if (e < E) csr[row_off[dst[e]] + rank[e]] = src[e];
}

// ---------------- GEMM1: H = x @ W1 (+ fused alpha1), head-split outputs ----------------
// 64 rows/block, 4 waves; wave w owns cols w*16..w*16+15. A staged f32 via
// global_load_lds (width 4), double-buffered K=64 blocks, LDS row stride 68 floats.
// Outputs: Hb0/Hb1 [N][32] bf16, asadA/asadB [N][8] bf16 ([0..3]=as,[4..7]=ad).
__global__ __launch_bounds__(256, 3) void k_gemm1(const float* __restrict__ x,
    const __bf16* __restrict__ w1h, const __bf16* __restrict__ w1l,
    const float* __restrict__ a_s, const float* __restrict__ a_d,
    __bf16* __restrict__ Hb0, __bf16* __restrict__ Hb1,
    __bf16* __restrict__ asadA, __bf16* __restrict__ asadB)
{
    __shared__ float As[2 * 64 * 68];        // 34.8 KB
    const int tid = threadIdx.x;
    const int w    = tid >> 6;
    const int lane = tid & 63;
    const int lr   = lane & 15;
    const int lk   = lane >> 4;
    const int rbase = blockIdx.x * 64;

    unsigned rowoff[16];
    #pragma unroll
    for (int i = 0; i < 16; ++i){
        int rg = rbase + w * 16 + i; if (rg >= NN) rg = NN - 1;
        rowoff[i] = (unsigned)rg * (unsigned)FIN + (unsigned)lane;
    }

    const __bf16* bh_p = w1h + (size_t)(w * 16 + lr) * KPAD + lk * 8;
    const __bf16* bl_p = w1l + (size_t)(w * 16 + lr) * KPAD + lk * 8;

    f32x4 acc[4] = {{0,0,0,0},{0,0,0,0},{0,0,0,0},{0,0,0,0}};

    #pragma unroll
    for (int i = 0; i < 16; ++i)
        gld_lds4(x + rowoff[i], &As[(w * 16 + i) * 68]);
    __syncthreads();

    for (int kb = 0; kb < 22; ++kb){
        const int cur = kb & 1;
        if (kb < 21){
            const float* gsrc = x + (kb + 1) * 64;
            float* lb = &As[(1 - cur) * 4352];
            #pragma unroll
            for (int i = 0; i < 16; ++i)
                gld_lds4(gsrc + rowoff[i], lb + (w * 16 + i) * 68);
        }
        const int kA = kb * 64;
        bf16x8 bh0 = *(const bf16x8*)(bh_p + kA);
        bf16x8 bl0 = *(const bf16x8*)(bl_p + kA);
        bf16x8 bh1 = *(const bf16x8*)(bh_p + kA + 32);
        bf16x8 bl1 = *(const bf16x8*)(bl_p + kA + 32);
        const float* ab = &As[cur * 4352] + lk * 8;
        #pragma unroll
        for (int ks = 0; ks < 2; ++ks){
            bf16x8 bh = ks ? bh1 : bh0;
            bf16x8 bl = ks ? bl1 : bl0;
            #pragma unroll
            for (int t = 0; t < 4; ++t){
                const float* p = ab + (t * 16 + lr) * 68 + ks * 32;
                f32x4 v0 = *(const f32x4*)p;
                f32x4 v1 = *(const f32x4*)(p + 4);
                bf16x8 ah, al;
                #pragma unroll
                for (int e = 0; e < 4; ++e){
                    __bf16 h0 = (__bf16)v0[e];
                    ah[e]     = h0; al[e]     = (__bf16)(v0[e] - (float)h0);
                    __bf16 h1 = (__bf16)v1[e];
                    ah[e + 4] = h1; al[e + 4] = (__bf16)(v1[e] - (float)h1);
                }
                acc[t] = __builtin_amdgcn_mfma_f32_16x16x32_bf16(ah, bh, acc[t], 0, 0, 0);
                acc[t] = __builtin_amdgcn_mfma_f32_16x16x32_bf16(al, bh, acc[t], 0, 0, 0);
                acc[t] = __builtin_amdgcn_mfma_f32_16x16x32_bf16(ah, bl, acc[t], 0, 0, 0);
            }
        }
        __syncthreads();
    }

    // peeled masked tail: k 1408..1439 (valid < 1433)
    {
        bf16x8 bh = *(const bf16x8*)(bh_p + 1408);
        bf16x8 bl = *(const bf16x8*)(bl_p + 1408);
        #pragma unroll
        for (int t = 0; t < 4; ++t){
            int rg = rbase + t * 16 + lr; if (rg >= NN) rg = NN - 1;
            const float* xr = x + (size_t)rg * FIN;
            bf16x8 ah, al;
            #pragma unroll
            for (int e = 0; e < 8; ++e){
                int k = 1408 + lk * 8 + e;
                float v = (k < FIN) ? xr[k] : 0.f;
                __bf16 h = (__bf16)v;
                ah[e] = h; al[e] = (__bf16)(v - (float)h);
            }
            acc[t] = __builtin_amdgcn_mfma_f32_16x16x32_bf16(ah, bh, acc[t], 0, 0, 0);
            acc[t] = __builtin_amdgcn_mfma_f32_16x16x32_bf16(al, bh, acc[t], 0, 0, 0);
            acc[t] = __builtin_amdgcn_mfma_f32_16x16x32_bf16(ah, bl, acc[t], 0, 0, 0);
        }
    }

    // epilogue 1: H tile -> LDS + bf16 head-half stores
    __syncthreads();
    const int col = w * 16 + lr;
    __bf16* hbp = (col < 32) ? Hb0 : Hb1;
    const int cc = col & 31;
    #pragma unroll
    for (int t = 0; t < 4; ++t){
        #pragma unroll
        for (int r = 0; r < 4; ++r){
            int rib = t * 16 + lk * 4 + r;
            float v = acc[t][r];
            As[rib * 68 + col] = v;
            int row = rbase + rib;
            if (row < NN) hbp[(size_t)row * 32 + cc] = (__bf16)v;
        }
    }
    __syncthreads();
    // epilogue 2: fused alpha1 -> bf16 asad records
    #pragma unroll
    for (int it = 0; it < 2; ++it){
        int task = tid + it * 256;
        int row  = task >> 3;
        int hh   = task & 7;
        int grow = rbase + row;
        if (grow < NN){
            const float* hr = &As[row * 68 + hh * 8];
            float s = 0.f, dd = 0.f;
            #pragma unroll
            for (int c = 0; c < 8; ++c){
                float v = hr[c];
                s  = fmaf(v, a_s[hh * 8 + c], s);
                dd = fmaf(v, a_d[hh * 8 + c], dd);
            }
            if (hh < 4){
                asadA[(size_t)grow * 8 + hh]     = (__bf16)s;
                asadA[(size_t)grow * 8 + 4 + hh] = (__bf16)dd;
            } else {
                asadB[(size_t)grow * 8 + (hh - 4)]     = (__bf16)s;
                asadB[(size_t)grow * 8 + 4 + (hh - 4)] = (__bf16)dd;
            }
        }
    }
}

// ---------------- layer-1 edge pass, one head-half per dispatch ----------------
// wave = 1 dst node; lane = (edge slot e2 = lane>>5) x (channel c = lane&31).
// Random WS per pass: HbP 3.2MB + asadP 0.8MB -> ~per-XCD L2.
__global__ __launch_bounds__(256, 6) void k_layer1p(const __bf16* __restrict__ asadP,
    const __bf16* __restrict__ HbP, const int* __restrict__ row_off, const int* __restrict__ csr,
    const float* __restrict__ b1P, float* __restrict__ x2, int colbase)
{
    const int d    = blockIdx.x * 4 + (threadIdx.x >> 6);
    const int lane = threadIdx.x & 63;
    const int e2   = lane >> 5;
    const int c    = lane & 31;
    const int h    = c >> 3;
    const float adv = (float)asadP[(size_t)d * 8 + 4 + h];
    float den, acc;
    {
        float as_d = (float)asadP[(size_t)d * 8 + h];
        float e0 = leaky02(as_d + adv);
        float p0 = __expf(e0 - 20.f);            // fixed-offset softmax (e bounded << 20)
        den = e2 ? 0.f : p0;
        acc = e2 ? 0.f : p0 * (float)HbP[(size_t)d * 32 + c];
    }
    const int beg = row_off[d], end = row_off[d + 1];
    const int nfull = (end - beg) >> 4;
    const int* cp = csr + beg + e2;

    float pa[8], hb[8];
    if (nfull > 0){
        #pragma unroll
        for (int t = 0; t < 8; ++t){
            int s = __builtin_nontemporal_load(cp + 2 * t);
            pa[t] = (float)asadP[(size_t)s * 8 + h];
            hb[t] = (float)HbP[(size_t)s * 32 + c];
        }
        for (int b = 1; b < nfull; ++b){
            float npa[8], nhb[8];
            const int* cpb = cp + b * 16;
            #pragma unroll
            for (int t = 0; t < 8; ++t){
                int s = __builtin_nontemporal_load(cpb + 2 * t);
                npa[t] = (float)asadP[(size_t)s * 8 + h];
                nhb[t] = (float)HbP[(size_t)s * 32 + c];
            }
            #pragma unroll
            for (int t = 0; t < 8; ++t){
                float e = leaky02(pa[t] + adv);
                float p = __expf(e - 20.f);
                den += p; acc = fmaf(p, hb[t], acc);
            }
            #pragma unroll
            for (int t = 0; t < 8; ++t){ pa[t] = npa[t]; hb[t] = nhb[t]; }
        }
        #pragma unroll
        for (int t = 0; t < 8; ++t){
            float e = leaky02(pa[t] + adv);
            float p = __expf(e - 20.f);
            den += p; acc = fmaf(p, hb[t], acc);
        }
    }
    {   // tail (0..15 edges), masked
        int tb = beg + nfull * 16;
        int tc = end - tb;
        if (tc > 0){
            #pragma unroll
            for (int t = 0; t < 8; ++t){
                int j = 2 * t + e2;
                int idx = tb + (j < tc ? j : tc - 1);
                int s = __builtin_nontemporal_load(csr + idx);
                float pav = (float)asadP[(size_t)s * 8 + h];
                float hbv = (float)HbP[(size_t)s * 32 + c];
                if (j < tc){
                    float e = leaky02(pav + adv);
                    float p = __expf(e - 20.f);
                    den += p; acc = fmaf(p, hbv, acc);
                }
            }
        }
    }
    acc += __shfl_xor(acc, 32, 64);
    den += __shfl_xor(den, 32, 64);
    if (e2 == 0){
        float o = acc / den + b1P[c];
        x2[(size_t)d * 64 + colbase + c] = (o > 0.f) ? o : (__expf(o) - 1.f);   // ELU fused
    }
}

// ---------------- GEMM2 + attention logits, layer 2 ----------------
// h2a[n][8]: [0..6] = h2 channels, [7] = as2 (packed record, one gather/edge later)
__global__ __launch_bounds__(256) void k_gemm2(const float* __restrict__ x2, const float* __restrict__ W2,
    const float* __restrict__ aw_in, const float* __restrict__ dw_in,
    float* __restrict__ h2a, float* __restrict__ ad2)
{
    __shared__ float w2s[448];
    __shared__ float aw[7], dw[7];
    int tid = threadIdx.x;
    for (int i = tid; i < 448; i += 256) w2s[i] = W2[i];
    if (tid < 7){ aw[tid] = aw_in[tid]; dw[tid] = dw_in[tid]; }
    __syncthreads();
    int n = blockIdx.x * 256 + tid;
    if (n >= NN) return;
    const float4* xp = (const float4*)(x2 + (size_t)n * 64);
    float acc[7] = {0.f,0.f,0.f,0.f,0.f,0.f,0.f};
    #pragma unroll
    for (int q = 0; q < 16; ++q){
        float4 v = xp[q];
        float vv[4] = {v.x, v.y, v.z, v.w};
        #pragma unroll
        for (int u = 0; u < 4; ++u){
            int k = q * 4 + u;
            #pragma unroll
            for (int c = 0; c < 7; ++c) acc[c] = fmaf(vv[u], w2s[k * 7 + c], acc[c]);
        }
    }
    float s = 0.f, d = 0.f;
    #pragma unroll
    for (int c = 0; c < 7; ++c){ s = fmaf(acc[c], aw[c], s); d = fmaf(acc[c], dw[c], d); }
    float* hp = h2a + (size_t)n * 8;
    #pragma unroll
    for (int c = 0; c < 7; ++c) hp[c] = acc[c];
    hp[7] = s;                                  // as2 packed into the record
    ad2[n] = d;
}

// ---------------- layer-2 edge pass + bias + log_softmax: 8 lanes/node, 16-edge batches ----------------
__global__ __launch_bounds__(256) void k_layer2(const float* __restrict__ ad2,
    const float* __restrict__ h2a, const int* __restrict__ row_off, const int* __restrict__ csr,
    const float* __restrict__ b2, float* __restrict__ out)
{
    int tid  = threadIdx.x;
    int node = blockIdx.x * 32 + (tid >> 3);
    int c    = tid & 7;
    int lane = tid & 63;
    int gb   = lane & ~7;                        // 8-lane group base within wave
    if (node >= NN) return;
    float adv   = ad2[node];
    float vself = h2a[(size_t)node * 8 + c];
    float as_n  = __shfl(vself, gb + 7, 64);
    float e0 = leaky02(as_n + adv);
    float p0 = __expf(e0 - 20.f);
    float den = p0;
    float acc = p0 * vself;                      // c==7 lane accumulates garbage; unused
    int beg = row_off[node], end = row_off[node + 1];
    for (int base = beg; base < end; base += 16){
        int cnt = end - base; if (cnt > 16) cnt = 16;
        int j1  = 8 + c;
        int cs0 = csr[base + (c  < cnt ? c  : cnt - 1)];
        int cs1 = csr[base + (j1 < cnt ? j1 : cnt - 1)];
        float val[16];
        #pragma unroll
        for (int t = 0; t < 16; ++t){
            if (t < cnt){
                int s = (t < 8) ? __shfl(cs0, gb + t, 64) : __shfl(cs1, gb + t - 8, 64);
                val[t] = h2a[(size_t)s * 8 + c];
            }
        }
        #pragma unroll
        for (int t = 0; t < 16; ++t){
            if (t < cnt){
                float as_s = __shfl(val[t], gb + 7, 64);
                float e = leaky02(as_s + adv);
                float p = __expf(e - 20.f);
                den += p;
                acc  = fmaf(p, val[t], acc);
            }
        }
    }
    float v = (c < 7) ? (acc / den + b2[c]) : -1e30f;
    float m = v;
    m = fmaxf(m, __shfl_xor(m, 1, 64));
    m = fmaxf(m, __shfl_xor(m, 2, 64));
    m = fmaxf(m, __shfl_xor(m, 4, 64));
    float ex = (c < 7) ? __expf(v - m) : 0.f;
    float s7 = ex;
    s7 += __shfl_xor(s7, 1, 64);
    s7 += __shfl_xor(s7, 2, 64);
    s7 += __shfl_xor(s7, 4, 64);
    if (c < 7) out[(size_t)node * 7 + c] = v - m - __logf(s7);
}

// ---------------- launcher ----------------
extern "C" void kernel_launch(void* const* d_in, const int* in_sizes, int n_in,
                              void* d_out, int out_size, void* d_ws, size_t ws_size,
                              hipStream_t stream)
{
    (void)n_in; (void)out_size; (void)ws_size;
    const float* x      = (const float*)d_in[0];
    const int*   ei     = (const int*)d_in[1];
    const int    E      = in_sizes[1] / 2;
    const float* W1     = (const float*)d_in[2];
    const float* asrc1  = (const float*)d_in[3];
    const float* adst1  = (const float*)d_in[4];
    const float* b1     = (const float*)d_in[5];
    const float* W2     = (const float*)d_in[6];
    const float* asrc2  = (const float*)d_in[7];
    const float* adst2  = (const float*)d_in[8];
    const float* b2     = (const float*)d_in[9];
    float* out = (float*)d_out;

    char* p = (char*)d_ws;
    auto alloc = [&](size_t bytes) -> void* {
        void* r = (void*)p;
        p += (bytes + 255) & ~(size_t)255;
        return r;
    };
    int*    deg     = (int*)alloc((size_t)NN * 4);
    int*    row_off = (int*)alloc((size_t)(NN + 1) * 4);
    int*    rank    = (int*)alloc((size_t)E * 4);
    int*    bsum    = (int*)alloc((size_t)NB_SCAN * 4);
    int*    bofs    = (int*)alloc((size_t)NB_SCAN * 4);
    int*    csr     = (int*)alloc((size_t)E * 4);
    __bf16* w1h     = (__bf16*)alloc((size_t)64 * KPAD * 2);
    __bf16* w1l     = (__bf16*)alloc((size_t)64 * KPAD * 2);
    __bf16* Hb0     = (__bf16*)alloc((size_t)NN * 32 * 2);
    __bf16* Hb1     = (__bf16*)alloc((size_t)NN * 32 * 2);
    __bf16* asadA   = (__bf16*)alloc((size_t)NN * 8 * 2);
    __bf16* asadB   = (__bf16*)alloc((size_t)NN * 8 * 2);
    float*  x2      = (float*)alloc((size_t)NN * 64 * 4);
    float*  h2a     = (float*)alloc((size_t)NN * 8 * 4);
    float*  ad2     = (float*)alloc((size_t)NN * 4);

    const int* src = ei;
    const int* dst = ei + E;

    k_prep   <<<64 + NB_SCAN, 256, 0, stream>>>(W1, w1h, w1l, deg);
    k_rank   <<<(E + 255) / 256, 256, 0, stream>>>(dst, deg, rank, E);
    k_scan1  <<<NB_SCAN, 256, 0, stream>>>(deg, bsum);
    k_scan2  <<<1, 256, 0, stream>>>(bsum, bofs);
    k_scan3  <<<NB_SCAN, 256, 0, stream>>>(deg, bofs, row_off);
    k_scatter<<<(E + 255) / 256, 256, 0, stream>>>(src, dst, rank, row_off, csr, E);
    k_gemm1  <<<(NN + 63) / 64, 256, 0, stream>>>(x, w1h, w1l, asrc1, adst1,
                                                  Hb0, Hb1, asadA, asadB);
    k_layer1p<<<NN / 4, 256, 0, stream>>>(asadA, Hb0, row_off, csr, b1,      x2, 0);
    k_layer1p<<<NN / 4, 256, 0, stream>>>(asadB, Hb1, row_off, csr, b1 + 32, x2, 32);
    k_gemm2  <<<(NN + 255) / 256, 256, 0, stream>>>(x2, W2, asrc2, adst2, h2a, ad2);
    k_layer2 <<<(NN + 31) / 32, 256, 0, stream>>>(ad2, h2a, row_off, csr, b2, out);
}

// Round 9
// 352.893 us; speedup vs baseline: 2.1262x; 1.0389x over previous
//
#include <hip/hip_runtime.h>
#include <hip/hip_bf16.h>

static constexpr int NN      = 50000;
static constexpr int FIN     = 1433;
static constexpr int KPAD    = 1440;            // 45 * 32
static constexpr int NB_SCAN = (NN + 255) / 256; // 196

typedef __bf16 bf16x8 __attribute__((ext_vector_type(8)));
typedef float  f32x4  __attribute__((ext_vector_type(4)));

__device__ __forceinline__ float leaky02(float v){ return v >= 0.f ? v : 0.2f * v; }
__device__ __forceinline__ float bflo(unsigned u){ return __uint_as_float(u << 16); }
__device__ __forceinline__ float bfhi(unsigned u){ return __uint_as_float(u & 0xffff0000u); }

// async global->LDS, 4 bytes/lane: lane l writes lds_base + l*4
__device__ __forceinline__ void gld_lds4(const float* g, float* l){
    __builtin_amdgcn_global_load_lds(
        (const __attribute__((address_space(1))) unsigned int*)g,
        (__attribute__((address_space(3))) unsigned int*)l, 4, 0, 0);
}

// ---------------- prep: W1 transpose/split + deg zero, one dispatch ----------------
__global__ __launch_bounds__(256) void k_prep(const float* __restrict__ W1,
                                              __bf16* __restrict__ w1h, __bf16* __restrict__ w1l,
                                              int* __restrict__ deg){
    int bid = blockIdx.x;
    if (bid < 64){
        int c = bid;                          // output column
        for (int k = threadIdx.x; k < KPAD; k += 256){
            float v = (k < FIN) ? W1[(size_t)k * 64 + c] : 0.f;
            __bf16 hi = (__bf16)v;
            w1h[(size_t)c * KPAD + k] = hi;
            w1l[(size_t)c * KPAD + k] = (__bf16)(v - (float)hi);
        }
    } else {
        int i = (bid - 64) * 256 + threadIdx.x;
        if (i < NN) deg[i] = 0;
    }
}

// ---------------- CSR build ----------------
// hist + per-edge rank in ONE atomic pass (separate kernel: do NOT fuse with gemm1,
// r7 showed fused regalloc spills the MFMA working set)
__global__ __launch_bounds__(256) void k_rank(const int* __restrict__ dst, int* __restrict__ deg,
                                              int* __restrict__ rank, int E){
    int e = blockIdx.x * 256 + threadIdx.x;
    if (e < E) rank[e] = atomicAdd(&deg[dst[e]], 1);
}

__global__ __launch_bounds__(256) void k_scan1(const int* __restrict__ deg, int* __restrict__ bsum){
    __shared__ int red[256];
    int i = blockIdx.x * 256 + threadIdx.x;
    red[threadIdx.x] = (i < NN) ? deg[i] : 0;
    __syncthreads();
    for (int off = 128; off > 0; off >>= 1){
        if (threadIdx.x < off) red[threadIdx.x] += red[threadIdx.x + off];
        __syncthreads();
    }
    if (threadIdx.x == 0) bsum[blockIdx.x] = red[0];
}

__global__ __launch_bounds__(256) void k_scan2(const int* __restrict__ bsum, int* __restrict__ bofs){
    __shared__ int s[256];
    int t = threadIdx.x;
    s[t] = (t < NB_SCAN) ? bsum[t] : 0;
    __syncthreads();
    for (int off = 1; off < 256; off <<= 1){
        int v = s[t];
        int a = (t >= off) ? s[t - off] : 0;
        __syncthreads();
        s[t] = v + a;
        __syncthreads();
    }
    if (t < NB_SCAN) bofs[t] = (t > 0) ? s[t - 1] : 0;
}

__global__ __launch_bounds__(256) void k_scan3(const int* __restrict__ deg, const int* __restrict__ bofs,
                                               int* __restrict__ row_off){
    __shared__ int s[256];
    int t = threadIdx.x;
    int i = blockIdx.x * 256 + t;
    int d = (i < NN) ? deg[i] : 0;
    s[t] = d;
    __syncthreads();
    for (int off = 1; off < 256; off <<= 1){
        int v = s[t];
        int a = (t >= off) ? s[t - off] : 0;
        __syncthreads();
        s[t] = v + a;
        __syncthreads();
    }
    int excl = s[t] - d + bofs[blockIdx.x];
    if (i < NN){
        row_off[i] = excl;
        if (i == NN - 1) row_off[NN] = excl + d;
    }
}

// atomic-free scatter using precomputed rank
__global__ __launch_bounds__(256) void k_scatter(const int* __restrict__ src, const int* __restrict__ dst,
                                                 const int* __restrict__ rank, const int* __restrict__ row_off,
                                                 int* __restrict__ csr, int E){
    int e = blockIdx.x * 256 + threadIdx.x;
    if (e < E) csr[row_off[dst[e]] + rank[e]] = src[e];
}

// ---------------- GEMM1: H = x @ W1 (+ fused alpha1), head-split outputs ----------------
// 64 rows/block, 4 waves; wave w owns cols w*16..w*16+15. A staged f32 via
// global_load_lds (width 4), double-buffered K=64 blocks, LDS row stride 68 floats.
// Outputs: Hb0/Hb1 [N][32] bf16, asadA/asadB [N][8] bf16 ([0..3]=as,[4..7]=ad).
__global__ __launch_bounds__(256, 3) void k_gemm1(const float* __restrict__ x,
    const __bf16* __restrict__ w1h, const __bf16* __restrict__ w1l,
    const float* __restrict__ a_s, const float* __restrict__ a_d,
    __bf16* __restrict__ Hb0, __bf16* __restrict__ Hb1,
    __bf16* __restrict__ asadA, __bf16* __restrict__ asadB)
{
    __shared__ float As[2 * 64 * 68];        // 34.8 KB
    const int tid = threadIdx.x;
    const int w    = tid >> 6;
    const int lane = tid & 63;
    const int lr   = lane & 15;
    const int lk   = lane >> 4;
    const int rbase = blockIdx.x * 64;

    unsigned rowoff[16];
    #pragma unroll
    for (int i = 0; i < 16; ++i){
        int rg = rbase + w * 16 + i; if (rg >= NN) rg = NN - 1;
        rowoff[i] = (unsigned)rg * (unsigned)FIN + (unsigned)lane;
    }

    const __bf16* bh_p = w1h + (size_t)(w * 16 + lr) * KPAD + lk * 8;
    const __bf16* bl_p = w1l + (size_t)(w * 16 + lr) * KPAD + lk * 8;

    f32x4 acc[4] = {{0,0,0,0},{0,0,0,0},{0,0,0,0},{0,0,0,0}};

    #pragma unroll
    for (int i = 0; i < 16; ++i)
        gld_lds4(x + rowoff[i], &As[(w * 16 + i) * 68]);
    __syncthreads();

    for (int kb = 0; kb < 22; ++kb){
        const int cur = kb & 1;
        if (kb < 21){
            const float* gsrc = x + (kb + 1) * 64;
            float* lb = &As[(1 - cur) * 4352];
            #pragma unroll
            for (int i = 0; i < 16; ++i)
                gld_lds4(gsrc + rowoff[i], lb + (w * 16 + i) * 68);
        }
        const int kA = kb * 64;
        bf16x8 bh0 = *(const bf16x8*)(bh_p + kA);
        bf16x8 bl0 = *(const bf16x8*)(bl_p + kA);
        bf16x8 bh1 = *(const bf16x8*)(bh_p + kA + 32);
        bf16x8 bl1 = *(const bf16x8*)(bl_p + kA + 32);
        const float* ab = &As[cur * 4352] + lk * 8;
        #pragma unroll
        for (int ks = 0; ks < 2; ++ks){
            bf16x8 bh = ks ? bh1 : bh0;
            bf16x8 bl = ks ? bl1 : bl0;
            #pragma unroll
            for (int t = 0; t < 4; ++t){
                const float* p = ab + (t * 16 + lr) * 68 + ks * 32;
                f32x4 v0 = *(const f32x4*)p;
                f32x4 v1 = *(const f32x4*)(p + 4);
                bf16x8 ah, al;
                #pragma unroll
                for (int e = 0; e < 4; ++e){
                    __bf16 h0 = (__bf16)v0[e];
                    ah[e]     = h0; al[e]     = (__bf16)(v0[e] - (float)h0);
                    __bf16 h1 = (__bf16)v1[e];
                    ah[e + 4] = h1; al[e + 4] = (__bf16)(v1[e] - (float)h1);
                }
                acc[t] = __builtin_amdgcn_mfma_f32_16x16x32_bf16(ah, bh, acc[t], 0, 0, 0);
                acc[t] = __builtin_amdgcn_mfma_f32_16x16x32_bf16(al, bh, acc[t], 0, 0, 0);
                acc[t] = __builtin_amdgcn_mfma_f32_16x16x32_bf16(ah, bl, acc[t], 0, 0, 0);
            }
        }
        __syncthreads();
    }

    // peeled masked tail: k 1408..1439 (valid < 1433)
    {
        bf16x8 bh = *(const bf16x8*)(bh_p + 1408);
        bf16x8 bl = *(const bf16x8*)(bl_p + 1408);
        #pragma unroll
        for (int t = 0; t < 4; ++t){
            int rg = rbase + t * 16 + lr; if (rg >= NN) rg = NN - 1;
            const float* xr = x + (size_t)rg * FIN;
            bf16x8 ah, al;
            #pragma unroll
            for (int e = 0; e < 8; ++e){
                int k = 1408 + lk * 8 + e;
                float v = (k < FIN) ? xr[k] : 0.f;
                __bf16 h = (__bf16)v;
                ah[e] = h; al[e] = (__bf16)(v - (float)h);
            }
            acc[t] = __builtin_amdgcn_mfma_f32_16x16x32_bf16(ah, bh, acc[t], 0, 0, 0);
            acc[t] = __builtin_amdgcn_mfma_f32_16x16x32_bf16(al, bh, acc[t], 0, 0, 0);
            acc[t] = __builtin_amdgcn_mfma_f32_16x16x32_bf16(ah, bl, acc[t], 0, 0, 0);
        }
    }

    // epilogue 1: H tile -> LDS + bf16 head-half stores
    __syncthreads();
    const int col = w * 16 + lr;
    __bf16* hbp = (col < 32) ? Hb0 : Hb1;
    const int cc = col & 31;
    #pragma unroll
    for (int t = 0; t < 4; ++t){
        #pragma unroll
        for (int r = 0; r < 4; ++r){
            int rib = t * 16 + lk * 4 + r;
            float v = acc[t][r];
            As[rib * 68 + col] = v;
            int row = rbase + rib;
            if (row < NN) hbp[(size_t)row * 32 + cc] = (__bf16)v;
        }
    }
    __syncthreads();
    // epilogue 2: fused alpha1 -> bf16 asad records
    #pragma unroll
    for (int it = 0; it < 2; ++it){
        int task = tid + it * 256;
        int row  = task >> 3;
        int hh   = task & 7;
        int grow = rbase + row;
        if (grow < NN){
            const float* hr = &As[row * 68 + hh * 8];
            float s = 0.f, dd = 0.f;
            #pragma unroll
            for (int c = 0; c < 8; ++c){
                float v = hr[c];
                s  = fmaf(v, a_s[hh * 8 + c], s);
                dd = fmaf(v, a_d[hh * 8 + c], dd);
            }
            if (hh < 4){
                asadA[(size_t)grow * 8 + hh]     = (__bf16)s;
                asadA[(size_t)grow * 8 + 4 + hh] = (__bf16)dd;
            } else {
                asadB[(size_t)grow * 8 + (hh - 4)]     = (__bf16)s;
                asadB[(size_t)grow * 8 + 4 + (hh - 4)] = (__bf16)dd;
            }
        }
    }
}

// ---------------- layer-1 edge pass, one head-half per dispatch ----------------
// wave = 1 dst node; lane l = (edge quarter q=l>>4) x (channel pair sl=l&15).
// One uint load = 2 bf16 channels -> one VMEM instr fetches 4 edges' H row.
// ~0.63 VMEM/edge/pass vs 2.0 before. Random WS per pass ~4MB -> per-XCD L2.
__global__ __launch_bounds__(256, 8) void k_layer1p(const __bf16* __restrict__ asadP,
    const __bf16* __restrict__ HbP, const int* __restrict__ row_off, const int* __restrict__ csr,
    const float* __restrict__ b1P, float* __restrict__ x2, int colbase)
{
    const int d  = blockIdx.x * 4 + (threadIdx.x >> 6);
    const int l  = threadIdx.x & 63;
    const int q  = l >> 4;           // edge slot within batch (0..3)
    const int sl = l & 15;           // channel pair index
    const int c0 = 2 * sl;
    const int h  = sl >> 2;          // head for both channels of the pair
    const float adv = (float)asadP[(size_t)d * 8 + 4 + h];

    float den = 0.f, a0 = 0.f, a1 = 0.f;
    if (q == 0){
        float as_d = (float)asadP[(size_t)d * 8 + h];
        float p0 = __expf(leaky02(as_d + adv) - 20.f);   // fixed-offset softmax (e << 20)
        unsigned hw = *(const unsigned*)&HbP[(size_t)d * 32 + c0];
        den = p0;
        a0 = p0 * bflo(hw);
        a1 = p0 * bfhi(hw);
    }

    const int beg = row_off[d], end = row_off[d + 1];
    const int nb = (end - beg + 7) >> 3;     // 8-edge batches
    int csrv = 0;
    if (nb > 0){
        int idx = beg + (l & 7); if (idx >= end) idx = end - 1;
        csrv = __builtin_nontemporal_load(csr + idx);
    }
    for (int b = 0; b < nb; ++b){
        const int base = beg + b * 8;
        int ncsr = 0;
        if (b + 1 < nb){
            int idx = base + 8 + (l & 7); if (idx >= end) idx = end - 1;
            ncsr = __builtin_nontemporal_load(csr + idx);
        }
        int s0 = __shfl(csrv, q, 8);
        int s1 = __shfl(csrv, 4 + q, 8);
        const bool v0 = (base + q) < end;
        const bool v1 = (base + 4 + q) < end;
        unsigned hw0 = 0, hw1 = 0; float av0 = 0.f, av1 = 0.f;
        if (v0){ hw0 = *(const unsigned*)&HbP[(size_t)s0 * 32 + c0];
                 av0 = (float)asadP[(size_t)s0 * 8 + h]; }
        if (v1){ hw1 = *(const unsigned*)&HbP[(size_t)s1 * 32 + c0];
                 av1 = (float)asadP[(size_t)s1 * 8 + h]; }
        if (v0){
            float p = __expf(leaky02(av0 + adv) - 20.f);
            den += p; a0 = fmaf(p, bflo(hw0), a0); a1 = fmaf(p, bfhi(hw0), a1);
        }
        if (v1){
            float p = __expf(leaky02(av1 + adv) - 20.f);
            den += p; a0 = fmaf(p, bflo(hw1), a0); a1 = fmaf(p, bfhi(hw1), a1);
        }
        csrv = ncsr;
    }

    // cross-quarter reduction (quarters processed disjoint edges)
    a0  += __shfl_xor(a0, 16, 64);  a0  += __shfl_xor(a0, 32, 64);
    a1  += __shfl_xor(a1, 16, 64);  a1  += __shfl_xor(a1, 32, 64);
    den += __shfl_xor(den, 16, 64); den += __shfl_xor(den, 32, 64);

    if (q == 0){
        float o0 = a0 / den + b1P[c0];
        float o1 = a1 / den + b1P[c0 + 1];
        o0 = (o0 > 0.f) ? o0 : (__expf(o0) - 1.f);       // ELU fused
        o1 = (o1 > 0.f) ? o1 : (__expf(o1) - 1.f);
        float2 ov = make_float2(o0, o1);
        *(float2*)&x2[(size_t)d * 64 + colbase + c0] = ov;
    }
}

// ---------------- GEMM2 + attention logits, layer 2 ----------------
// h2a[n][8]: [0..6] = h2 channels, [7] = as2 (packed record, one gather/edge later)
__global__ __launch_bounds__(256) void k_gemm2(const float* __restrict__ x2, const float* __restrict__ W2,
    const float* __restrict__ aw_in, const float* __restrict__ dw_in,
    float* __restrict__ h2a, float* __restrict__ ad2)
{
    __shared__ float w2s[448];
    __shared__ float aw[7], dw[7];
    int tid = threadIdx.x;
    for (int i = tid; i < 448; i += 256) w2s[i] = W2[i];
    if (tid < 7){ aw[tid] = aw_in[tid]; dw[tid] = dw_in[tid]; }
    __syncthreads();
    int n = blockIdx.x * 256 + tid;
    if (n >= NN) return;
    const float4* xp = (const float4*)(x2 + (size_t)n * 64);
    float acc[7] = {0.f,0.f,0.f,0.f,0.f,0.f,0.f};
    #pragma unroll
    for (int q = 0; q < 16; ++q){
        float4 v = xp[q];
        float vv[4] = {v.x, v.y, v.z, v.w};
        #pragma unroll
        for (int u = 0; u < 4; ++u){
            int k = q * 4 + u;
            #pragma unroll
            for (int c = 0; c < 7; ++c) acc[c] = fmaf(vv[u], w2s[k * 7 + c], acc[c]);
        }
    }
    float s = 0.f, d = 0.f;
    #pragma unroll
    for (int c = 0; c < 7; ++c){ s = fmaf(acc[c], aw[c], s); d = fmaf(acc[c], dw[c], d); }
    float* hp = h2a + (size_t)n * 8;
    #pragma unroll
    for (int c = 0; c < 7; ++c) hp[c] = acc[c];
    hp[7] = s;                                  // as2 packed into the record
    ad2[n] = d;
}

// ---------------- layer-2 edge pass + bias + log_softmax: 8 lanes/node, 16-edge batches ----------------
__global__ __launch_bounds__(256) void k_layer2(const float* __restrict__ ad2,
    const float* __restrict__ h2a, const int* __restrict__ row_off, const int* __restrict__ csr,
    const float* __restrict__ b2, float* __restrict__ out)
{
    int tid  = threadIdx.x;
    int node = blockIdx.x * 32 + (tid >> 3);
    int c    = tid & 7;
    int lane = tid & 63;
    int gb   = lane & ~7;                        // 8-lane group base within wave
    if (node >= NN) return;
    float adv   = ad2[node];
    float vself = h2a[(size_t)node * 8 + c];
    float as_n  = __shfl(vself, gb + 7, 64);
    float e0 = leaky02(as_n + adv);
    float p0 = __expf(e0 - 20.f);
    float den = p0;
    float acc = p0 * vself;                      // c==7 lane accumulates garbage; unused
    int beg = row_off[node], end = row_off[node + 1];
    for (int base = beg; base < end; base += 16){
        int cnt = end - base; if (cnt > 16) cnt = 16;
        int j1  = 8 + c;
        int cs0 = csr[base + (c  < cnt ? c  : cnt - 1)];
        int cs1 = csr[base + (j1 < cnt ? j1 : cnt - 1)];
        float val[16];
        #pragma unroll
        for (int t = 0; t < 16; ++t){
            if (t < cnt){
                int s = (t < 8) ? __shfl(cs0, gb + t, 64) : __shfl(cs1, gb + t - 8, 64);
                val[t] = h2a[(size_t)s * 8 + c];
            }
        }
        #pragma unroll
        for (int t = 0; t < 16; ++t){
            if (t < cnt){
                float as_s = __shfl(val[t], gb + 7, 64);
                float e = leaky02(as_s + adv);
                float p = __expf(e - 20.f);
                den += p;
                acc  = fmaf(p, val[t], acc);
            }
        }
    }
    float v = (c < 7) ? (acc / den + b2[c]) : -1e30f;
    float m = v;
    m = fmaxf(m, __shfl_xor(m, 1, 64));
    m = fmaxf(m, __shfl_xor(m, 2, 64));
    m = fmaxf(m, __shfl_xor(m, 4, 64));
    float ex = (c < 7) ? __expf(v - m) : 0.f;
    float s7 = ex;
    s7 += __shfl_xor(s7, 1, 64);
    s7 += __shfl_xor(s7, 2, 64);
    s7 += __shfl_xor(s7, 4, 64);
    if (c < 7) out[(size_t)node * 7 + c] = v - m - __logf(s7);
}

// ---------------- launcher ----------------
extern "C" void kernel_launch(void* const* d_in, const int* in_sizes, int n_in,
                              void* d_out, int out_size, void* d_ws, size_t ws_size,
                              hipStream_t stream)
{
    (void)n_in; (void)out_size; (void)ws_size;
    const float* x      = (const float*)d_in[0];
    const int*   ei     = (const int*)d_in[1];
    const int    E      = in_sizes[1] / 2;
    const float* W1     = (const float*)d_in[2];
    const float* asrc1  = (const float*)d_in[3];
    const float* adst1  = (const float*)d_in[4];
    const float* b1     = (const float*)d_in[5];
    const float* W2     = (const float*)d_in[6];
    const float* asrc2  = (const float*)d_in[7];
    const float* adst2  = (const float*)d_in[8];
    const float* b2     = (const float*)d_in[9];
    float* out = (float*)d_out;

    char* p = (char*)d_ws;
    auto alloc = [&](size_t bytes) -> void* {
        void* r = (void*)p;
        p += (bytes + 255) & ~(size_t)255;
        return r;
    };
    int*    deg     = (int*)alloc((size_t)NN * 4);
    int*    row_off = (int*)alloc((size_t)(NN + 1) * 4);
    int*    rank    = (int*)alloc((size_t)E * 4);
    int*    bsum    = (int*)alloc((size_t)NB_SCAN * 4);
    int*    bofs    = (int*)alloc((size_t)NB_SCAN * 4);
    int*    csr     = (int*)alloc((size_t)E * 4);
    __bf16* w1h     = (__bf16*)alloc((size_t)64 * KPAD * 2);
    __bf16* w1l     = (__bf16*)alloc((size_t)64 * KPAD * 2);
    __bf16* Hb0     = (__bf16*)alloc((size_t)NN * 32 * 2);
    __bf16* Hb1     = (__bf16*)alloc((size_t)NN * 32 * 2);
    __bf16* asadA   = (__bf16*)alloc((size_t)NN * 8 * 2);
    __bf16* asadB   = (__bf16*)alloc((size_t)NN * 8 * 2);
    float*  x2      = (float*)alloc((size_t)NN * 64 * 4);
    float*  h2a     = (float*)alloc((size_t)NN * 8 * 4);
    float*  ad2     = (float*)alloc((size_t)NN * 4);

    const int* src = ei;
    const int* dst = ei + E;

    k_prep   <<<64 + NB_SCAN, 256, 0, stream>>>(W1, w1h, w1l, deg);
    k_rank   <<<(E + 255) / 256, 256, 0, stream>>>(dst, deg, rank, E);
    k_scan1  <<<NB_SCAN, 256, 0, stream>>>(deg, bsum);
    k_scan2  <<<1, 256, 0, stream>>>(bsum, bofs);
    k_scan3  <<<NB_SCAN, 256, 0, stream>>>(deg, bofs, row_off);
    k_scatter<<<(E + 255) / 256, 256, 0, stream>>>(src, dst, rank, row_off, csr, E);
    k_gemm1  <<<(NN + 63) / 64, 256, 0, stream>>>(x, w1h, w1l, asrc1, adst1,
                                                  Hb0, Hb1, asadA, asadB);
    k_layer1p<<<NN / 4, 256, 0, stream>>>(asadA, Hb0, row_off, csr, b1,      x2, 0);
    k_layer1p<<<NN / 4, 256, 0, stream>>>(asadB, Hb1, row_off, csr, b1 + 32, x2, 32);
    k_gemm2  <<<(NN + 255) / 256, 256, 0, stream>>>(x2, W2, asrc2, adst2, h2a, ad2);
    k_layer2 <<<(NN + 31) / 32, 256, 0, stream>>>(ad2, h2a, row_off, csr, b2, out);
}

// Round 10
// 351.287 us; speedup vs baseline: 2.1359x; 1.0046x over previous
//
#include <hip/hip_runtime.h>
#include <hip/hip_bf16.h>

static constexpr int NN      = 50000;
static constexpr int FIN     = 1433;
static constexpr int KPAD    = 1440;            // 45 * 32
static constexpr int NB_SCAN = (NN + 255) / 256; // 196

typedef __bf16 bf16x8 __attribute__((ext_vector_type(8)));
typedef float  f32x4  __attribute__((ext_vector_type(4)));

__device__ __forceinline__ float leaky02(float v){ return v >= 0.f ? v : 0.2f * v; }
__device__ __forceinline__ float bflo(unsigned u){ return __uint_as_float(u << 16); }
__device__ __forceinline__ float bfhi(unsigned u){ return __uint_as_float(u & 0xffff0000u); }

// async global->LDS, 4 bytes/lane: lane l writes lds_base + l*4
__device__ __forceinline__ void gld_lds4(const float* g, float* l){
    __builtin_amdgcn_global_load_lds(
        (const __attribute__((address_space(1))) unsigned int*)g,
        (__attribute__((address_space(3))) unsigned int*)l, 4, 0, 0);
}

// ---------------- prep: W1 transpose/split + deg zero, one dispatch ----------------
__global__ __launch_bounds__(256) void k_prep(const float* __restrict__ W1,
                                              __bf16* __restrict__ w1h, __bf16* __restrict__ w1l,
                                              int* __restrict__ deg){
    int bid = blockIdx.x;
    if (bid < 64){
        int c = bid;                          // output column
        for (int k = threadIdx.x; k < KPAD; k += 256){
            float v = (k < FIN) ? W1[(size_t)k * 64 + c] : 0.f;
            __bf16 hi = (__bf16)v;
            w1h[(size_t)c * KPAD + k] = hi;
            w1l[(size_t)c * KPAD + k] = (__bf16)(v - (float)hi);
        }
    } else {
        int i = (bid - 64) * 256 + threadIdx.x;
        if (i < NN) deg[i] = 0;
    }
}

// ---------------- CSR build ----------------
// hist + per-edge rank in ONE atomic pass (separate kernel: do NOT fuse with gemm1,
// r7 showed fused regalloc spills the MFMA working set)
__global__ __launch_bounds__(256) void k_rank(const int* __restrict__ dst, int* __restrict__ deg,
                                              int* __restrict__ rank, int E){
    int e = blockIdx.x * 256 + threadIdx.x;
    if (e < E) rank[e] = atomicAdd(&deg[dst[e]], 1);
}

__global__ __launch_bounds__(256) void k_scan1(const int* __restrict__ deg, int* __restrict__ bsum){
    __shared__ int red[256];
    int i = blockIdx.x * 256 + threadIdx.x;
    red[threadIdx.x] = (i < NN) ? deg[i] : 0;
    __syncthreads();
    for (int off = 128; off > 0; off >>= 1){
        if (threadIdx.x < off) red[threadIdx.x] += red[threadIdx.x + off];
        __syncthreads();
    }
    if (threadIdx.x == 0) bsum[blockIdx.x] = red[0];
}

__global__ __launch_bounds__(256) void k_scan2(const int* __restrict__ bsum, int* __restrict__ bofs){
    __shared__ int s[256];
    int t = threadIdx.x;
    s[t] = (t < NB_SCAN) ? bsum[t] : 0;
    __syncthreads();
    for (int off = 1; off < 256; off <<= 1){
        int v = s[t];
        int a = (t >= off) ? s[t - off] : 0;
        __syncthreads();
        s[t] = v + a;
        __syncthreads();
    }
    if (t < NB_SCAN) bofs[t] = (t > 0) ? s[t - 1] : 0;
}

__global__ __launch_bounds__(256) void k_scan3(const int* __restrict__ deg, const int* __restrict__ bofs,
                                               int* __restrict__ row_off){
    __shared__ int s[256];
    int t = threadIdx.x;
    int i = blockIdx.x * 256 + t;
    int d = (i < NN) ? deg[i] : 0;
    s[t] = d;
    __syncthreads();
    for (int off = 1; off < 256; off <<= 1){
        int v = s[t];
        int a = (t >= off) ? s[t - off] : 0;
        __syncthreads();
        s[t] = v + a;
        __syncthreads();
    }
    int excl = s[t] - d + bofs[blockIdx.x];
    if (i < NN){
        row_off[i] = excl;
        if (i == NN - 1) row_off[NN] = excl + d;
    }
}

// atomic-free scatter using precomputed rank
__global__ __launch_bounds__(256) void k_scatter(const int* __restrict__ src, const int* __restrict__ dst,
                                                 const int* __restrict__ rank, const int* __restrict__ row_off,
                                                 int* __restrict__ csr, int E){
    int e = blockIdx.x * 256 + threadIdx.x;
    if (e < E) csr[row_off[dst[e]] + rank[e]] = src[e];
}

// ---------------- GEMM1: H = x @ W1 (+ fused alpha1), head-split outputs ----------------
// 64 rows/block, 4 waves; wave w owns cols w*16..w*16+15.
// 3-phase pipeline: (1) async f32 stage into As (gld_lds4), (2) cooperative one-time
// bf16 hi/lo convert As -> AH/AL planes, (3) compute reads AH/AL with ZERO convert VALU.
// As (f32, single) + AH/AL act as the double buffer. LDS 35.8KB -> 4 blocks/CU.
__global__ __launch_bounds__(256, 4) void k_gemm1(const float* __restrict__ x,
    const __bf16* __restrict__ w1h, const __bf16* __restrict__ w1l,
    const float* __restrict__ a_s, const float* __restrict__ a_d,
    __bf16* __restrict__ Hb0, __bf16* __restrict__ Hb1,
    __bf16* __restrict__ asadA, __bf16* __restrict__ asadB)
{
    __shared__ float  As[64 * 68];           // 17.4 KB f32 staging (stride 68)
    __shared__ __bf16 AH[64 * 72];           // 9.2 KB hi plane (stride 72)
    __shared__ __bf16 AL[64 * 72];           // 9.2 KB lo plane
    const int tid  = threadIdx.x;
    const int w    = tid >> 6;
    const int lane = tid & 63;
    const int lr   = lane & 15;
    const int lk   = lane >> 4;
    const int rbase = blockIdx.x * 64;
    // convert-phase role: thread handles row cr, 16 cols starting at cg
    const int cr = tid >> 2;
    const int cg = (tid & 3) * 16;

    unsigned rowoff[16];
    #pragma unroll
    for (int i = 0; i < 16; ++i){
        int rg = rbase + w * 16 + i; if (rg >= NN) rg = NN - 1;
        rowoff[i] = (unsigned)rg * (unsigned)FIN + (unsigned)lane;
    }

    const __bf16* bh_p = w1h + (size_t)(w * 16 + lr) * KPAD + lk * 8;
    const __bf16* bl_p = w1l + (size_t)(w * 16 + lr) * KPAD + lk * 8;

    f32x4 acc[4] = {{0,0,0,0},{0,0,0,0},{0,0,0,0},{0,0,0,0}};

    // prologue: stage kb=0 into As
    #pragma unroll
    for (int i = 0; i < 16; ++i)
        gld_lds4(x + rowoff[i], &As[(w * 16 + i) * 68]);
    __syncthreads();                          // vmcnt drained: As = kb 0

    for (int kb = 0; kb < 22; ++kb){
        // phase 2: one-time convert As -> AH/AL (each element converted ONCE)
        {
            const float* rp = &As[cr * 68 + cg];
            f32x4 v[4];
            #pragma unroll
            for (int j = 0; j < 4; ++j) v[j] = *(const f32x4*)(rp + j * 4);
            bf16x8 hv0, hv1, lv0, lv1;
            #pragma unroll
            for (int j = 0; j < 2; ++j){
                #pragma unroll
                for (int e = 0; e < 4; ++e){
                    float a0 = v[2 * j][e], a1 = v[2 * j + 1][e];
                    __bf16 h0 = (__bf16)a0, h1 = (__bf16)a1;
                    if (j == 0){ hv0[e] = h0; hv0[e + 4] = h1;
                                 lv0[e] = (__bf16)(a0 - (float)h0);
                                 lv0[e + 4] = (__bf16)(a1 - (float)h1); }
                    else       { hv1[e] = h0; hv1[e + 4] = h1;
                                 lv1[e] = (__bf16)(a0 - (float)h0);
                                 lv1[e + 4] = (__bf16)(a1 - (float)h1); }
                }
            }
            // interleave back: v[0..1] are cols cg..cg+7? NO: v[j] is cols cg+4j..cg+4j+3
            // hv0 holds cols {cg..cg+3, cg+4..cg+7} = cg..cg+7 contiguous ✓
            *(bf16x8*)&AH[cr * 72 + cg]     = hv0;
            *(bf16x8*)&AH[cr * 72 + cg + 8] = hv1;
            *(bf16x8*)&AL[cr * 72 + cg]     = lv0;
            *(bf16x8*)&AL[cr * 72 + cg + 8] = lv1;
        }
        __syncthreads();                      // AH/AL ready; As free for overwrite

        // phase 1: async stage kb+1 into As (overlaps with compute below)
        if (kb < 21){
            const float* gsrc = x + (kb + 1) * 64;
            #pragma unroll
            for (int i = 0; i < 16; ++i)
                gld_lds4(gsrc + rowoff[i], &As[(w * 16 + i) * 68]);
        }

        // phase 3: compute from AH/AL (no conversion VALU)
        const int kA = kb * 64;
        bf16x8 bh0 = *(const bf16x8*)(bh_p + kA);
        bf16x8 bl0 = *(const bf16x8*)(bl_p + kA);
        bf16x8 bh1 = *(const bf16x8*)(bh_p + kA + 32);
        bf16x8 bl1 = *(const bf16x8*)(bl_p + kA + 32);
        #pragma unroll
        for (int ks = 0; ks < 2; ++ks){
            bf16x8 bh = ks ? bh1 : bh0;
            bf16x8 bl = ks ? bl1 : bl0;
            #pragma unroll
            for (int t = 0; t < 4; ++t){
                const int ao = (t * 16 + lr) * 72 + ks * 32 + lk * 8;
                bf16x8 ah = *(const bf16x8*)&AH[ao];
                bf16x8 al = *(const bf16x8*)&AL[ao];
                acc[t] = __builtin_amdgcn_mfma_f32_16x16x32_bf16(ah, bh, acc[t], 0, 0, 0);
                acc[t] = __builtin_amdgcn_mfma_f32_16x16x32_bf16(al, bh, acc[t], 0, 0, 0);
                acc[t] = __builtin_amdgcn_mfma_f32_16x16x32_bf16(ah, bl, acc[t], 0, 0, 0);
            }
        }
        __syncthreads();                      // staging drained; AH/AL consumed
    }

    // peeled masked tail: k 1408..1439 (valid < 1433), direct loads
    {
        bf16x8 bh = *(const bf16x8*)(bh_p + 1408);
        bf16x8 bl = *(const bf16x8*)(bl_p + 1408);
        #pragma unroll
        for (int t = 0; t < 4; ++t){
            int rg = rbase + t * 16 + lr; if (rg >= NN) rg = NN - 1;
            const float* xr = x + (size_t)rg * FIN;
            bf16x8 ah, al;
            #pragma unroll
            for (int e = 0; e < 8; ++e){
                int k = 1408 + lk * 8 + e;
                float v = (k < FIN) ? xr[k] : 0.f;
                __bf16 h = (__bf16)v;
                ah[e] = h; al[e] = (__bf16)(v - (float)h);
            }
            acc[t] = __builtin_amdgcn_mfma_f32_16x16x32_bf16(ah, bh, acc[t], 0, 0, 0);
            acc[t] = __builtin_amdgcn_mfma_f32_16x16x32_bf16(al, bh, acc[t], 0, 0, 0);
            acc[t] = __builtin_amdgcn_mfma_f32_16x16x32_bf16(ah, bl, acc[t], 0, 0, 0);
        }
    }

    // epilogue 1: H tile -> LDS (As, f32) + bf16 head-half stores
    __syncthreads();
    const int col = w * 16 + lr;
    __bf16* hbp = (col < 32) ? Hb0 : Hb1;
    const int cc = col & 31;
    #pragma unroll
    for (int t = 0; t < 4; ++t){
        #pragma unroll
        for (int r = 0; r < 4; ++r){
            int rib = t * 16 + lk * 4 + r;
            float v = acc[t][r];
            As[rib * 68 + col] = v;
            int row = rbase + rib;
            if (row < NN) hbp[(size_t)row * 32 + cc] = (__bf16)v;
        }
    }
    __syncthreads();
    // epilogue 2: fused alpha1 -> bf16 asad records
    #pragma unroll
    for (int it = 0; it < 2; ++it){
        int task = tid + it * 256;
        int row  = task >> 3;
        int hh   = task & 7;
        int grow = rbase + row;
        if (grow < NN){
            const float* hr = &As[row * 68 + hh * 8];
            float s = 0.f, dd = 0.f;
            #pragma unroll
            for (int c = 0; c < 8; ++c){
                float v = hr[c];
                s  = fmaf(v, a_s[hh * 8 + c], s);
                dd = fmaf(v, a_d[hh * 8 + c], dd);
            }
            if (hh < 4){
                asadA[(size_t)grow * 8 + hh]     = (__bf16)s;
                asadA[(size_t)grow * 8 + 4 + hh] = (__bf16)dd;
            } else {
                asadB[(size_t)grow * 8 + (hh - 4)]     = (__bf16)s;
                asadB[(size_t)grow * 8 + 4 + (hh - 4)] = (__bf16)dd;
            }
        }
    }
}

// ---------------- layer-1 edge pass, one head-half per dispatch ----------------
// wave = 1 dst node; lane l = (edge quarter q=l>>4) x (channel pair sl=l&15).
// One uint load = 2 bf16 channels -> one VMEM instr fetches 4 edges' H row.
__global__ __launch_bounds__(256, 8) void k_layer1p(const __bf16* __restrict__ asadP,
    const __bf16* __restrict__ HbP, const int* __restrict__ row_off, const int* __restrict__ csr,
    const float* __restrict__ b1P, float* __restrict__ x2, int colbase)
{
    const int d  = blockIdx.x * 4 + (threadIdx.x >> 6);
    const int l  = threadIdx.x & 63;
    const int q  = l >> 4;           // edge slot within batch (0..3)
    const int sl = l & 15;           // channel pair index
    const int c0 = 2 * sl;
    const int h  = sl >> 2;          // head for both channels of the pair
    const float adv = (float)asadP[(size_t)d * 8 + 4 + h];

    float den = 0.f, a0 = 0.f, a1 = 0.f;
    if (q == 0){
        float as_d = (float)asadP[(size_t)d * 8 + h];
        float p0 = __expf(leaky02(as_d + adv) - 20.f);   // fixed-offset softmax (e << 20)
        unsigned hw = *(const unsigned*)&HbP[(size_t)d * 32 + c0];
        den = p0;
        a0 = p0 * bflo(hw);
        a1 = p0 * bfhi(hw);
    }

    const int beg = row_off[d], end = row_off[d + 1];
    const int nb = (end - beg + 7) >> 3;     // 8-edge batches
    int csrv = 0;
    if (nb > 0){
        int idx = beg + (l & 7); if (idx >= end) idx = end - 1;
        csrv = __builtin_nontemporal_load(csr + idx);
    }
    for (int b = 0; b < nb; ++b){
        const int base = beg + b * 8;
        int ncsr = 0;
        if (b + 1 < nb){
            int idx = base + 8 + (l & 7); if (idx >= end) idx = end - 1;
            ncsr = __builtin_nontemporal_load(csr + idx);
        }
        int s0 = __shfl(csrv, q, 8);
        int s1 = __shfl(csrv, 4 + q, 8);
        const bool v0 = (base + q) < end;
        const bool v1 = (base + 4 + q) < end;
        unsigned hw0 = 0, hw1 = 0; float av0 = 0.f, av1 = 0.f;
        if (v0){ hw0 = *(const unsigned*)&HbP[(size_t)s0 * 32 + c0];
                 av0 = (float)asadP[(size_t)s0 * 8 + h]; }
        if (v1){ hw1 = *(const unsigned*)&HbP[(size_t)s1 * 32 + c0];
                 av1 = (float)asadP[(size_t)s1 * 8 + h]; }
        if (v0){
            float p = __expf(leaky02(av0 + adv) - 20.f);
            den += p; a0 = fmaf(p, bflo(hw0), a0); a1 = fmaf(p, bfhi(hw0), a1);
        }
        if (v1){
            float p = __expf(leaky02(av1 + adv) - 20.f);
            den += p; a0 = fmaf(p, bflo(hw1), a0); a1 = fmaf(p, bfhi(hw1), a1);
        }
        csrv = ncsr;
    }

    // cross-quarter reduction (quarters processed disjoint edges)
    a0  += __shfl_xor(a0, 16, 64);  a0  += __shfl_xor(a0, 32, 64);
    a1  += __shfl_xor(a1, 16, 64);  a1  += __shfl_xor(a1, 32, 64);
    den += __shfl_xor(den, 16, 64); den += __shfl_xor(den, 32, 64);

    if (q == 0){
        float o0 = a0 / den + b1P[c0];
        float o1 = a1 / den + b1P[c0 + 1];
        o0 = (o0 > 0.f) ? o0 : (__expf(o0) - 1.f);       // ELU fused
        o1 = (o1 > 0.f) ? o1 : (__expf(o1) - 1.f);
        float2 ov = make_float2(o0, o1);
        *(float2*)&x2[(size_t)d * 64 + colbase + c0] = ov;
    }
}

// ---------------- GEMM2 + attention logits, layer 2 ----------------
// h2a[n][8]: [0..6] = h2 channels, [7] = as2 (packed record, one gather/edge later)
__global__ __launch_bounds__(256) void k_gemm2(const float* __restrict__ x2, const float* __restrict__ W2,
    const float* __restrict__ aw_in, const float* __restrict__ dw_in,
    float* __restrict__ h2a, float* __restrict__ ad2)
{
    __shared__ float w2s[448];
    __shared__ float aw[7], dw[7];
    int tid = threadIdx.x;
    for (int i = tid; i < 448; i += 256) w2s[i] = W2[i];
    if (tid < 7){ aw[tid] = aw_in[tid]; dw[tid] = dw_in[tid]; }
    __syncthreads();
    int n = blockIdx.x * 256 + tid;
    if (n >= NN) return;
    const float4* xp = (const float4*)(x2 + (size_t)n * 64);
    float acc[7] = {0.f,0.f,0.f,0.f,0.f,0.f,0.f};
    #pragma unroll
    for (int q = 0; q < 16; ++q){
        float4 v = xp[q];
        float vv[4] = {v.x, v.y, v.z, v.w};
        #pragma unroll
        for (int u = 0; u < 4; ++u){
            int k = q * 4 + u;
            #pragma unroll
            for (int c = 0; c < 7; ++c) acc[c] = fmaf(vv[u], w2s[k * 7 + c], acc[c]);
        }
    }
    float s = 0.f, d = 0.f;
    #pragma unroll
    for (int c = 0; c < 7; ++c){ s = fmaf(acc[c], aw[c], s); d = fmaf(acc[c], dw[c], d); }
    float* hp = h2a + (size_t)n * 8;
    #pragma unroll
    for (int c = 0; c < 7; ++c) hp[c] = acc[c];
    hp[7] = s;                                  // as2 packed into the record
    ad2[n] = d;
}

// ---------------- layer-2 edge pass + bias + log_softmax: 8 lanes/node, 16-edge batches ----------------
__global__ __launch_bounds__(256) void k_layer2(const float* __restrict__ ad2,
    const float* __restrict__ h2a, const int* __restrict__ row_off, const int* __restrict__ csr,
    const float* __restrict__ b2, float* __restrict__ out)
{
    int tid  = threadIdx.x;
    int node = blockIdx.x * 32 + (tid >> 3);
    int c    = tid & 7;
    int lane = tid & 63;
    int gb   = lane & ~7;                        // 8-lane group base within wave
    if (node >= NN) return;
    float adv   = ad2[node];
    float vself = h2a[(size_t)node * 8 + c];
    float as_n  = __shfl(vself, gb + 7, 64);
    float e0 = leaky02(as_n + adv);
    float p0 = __expf(e0 - 20.f);
    float den = p0;
    float acc = p0 * vself;                      // c==7 lane accumulates garbage; unused
    int beg = row_off[node], end = row_off[node + 1];
    for (int base = beg; base < end; base += 16){
        int cnt = end - base; if (cnt > 16) cnt = 16;
        int j1  = 8 + c;
        int cs0 = csr[base + (c  < cnt ? c  : cnt - 1)];
        int cs1 = csr[base + (j1 < cnt ? j1 : cnt - 1)];
        float val[16];
        #pragma unroll
        for (int t = 0; t < 16; ++t){
            if (t < cnt){
                int s = (t < 8) ? __shfl(cs0, gb + t, 64) : __shfl(cs1, gb + t - 8, 64);
                val[t] = h2a[(size_t)s * 8 + c];
            }
        }
        #pragma unroll
        for (int t = 0; t < 16; ++t){
            if (t < cnt){
                float as_s = __shfl(val[t], gb + 7, 64);
                float e = leaky02(as_s + adv);
                float p = __expf(e - 20.f);
                den += p;
                acc  = fmaf(p, val[t], acc);
            }
        }
    }
    float v = (c < 7) ? (acc / den + b2[c]) : -1e30f;
    float m = v;
    m = fmaxf(m, __shfl_xor(m, 1, 64));
    m = fmaxf(m, __shfl_xor(m, 2, 64));
    m = fmaxf(m, __shfl_xor(m, 4, 64));
    float ex = (c < 7) ? __expf(v - m) : 0.f;
    float s7 = ex;
    s7 += __shfl_xor(s7, 1, 64);
    s7 += __shfl_xor(s7, 2, 64);
    s7 += __shfl_xor(s7, 4, 64);
    if (c < 7) out[(size_t)node * 7 + c] = v - m - __logf(s7);
}

// ---------------- launcher ----------------
extern "C" void kernel_launch(void* const* d_in, const int* in_sizes, int n_in,
                              void* d_out, int out_size, void* d_ws, size_t ws_size,
                              hipStream_t stream)
{
    (void)n_in; (void)out_size; (void)ws_size;
    const float* x      = (const float*)d_in[0];
    const int*   ei     = (const int*)d_in[1];
    const int    E      = in_sizes[1] / 2;
    const float* W1     = (const float*)d_in[2];
    const float* asrc1  = (const float*)d_in[3];
    const float* adst1  = (const float*)d_in[4];
    const float* b1     = (const float*)d_in[5];
    const float* W2     = (const float*)d_in[6];
    const float* asrc2  = (const float*)d_in[7];
    const float* adst2  = (const float*)d_in[8];
    const float* b2     = (const float*)d_in[9];
    float* out = (float*)d_out;

    char* p = (char*)d_ws;
    auto alloc = [&](size_t bytes) -> void* {
        void* r = (void*)p;
        p += (bytes + 255) & ~(size_t)255;
        return r;
    };
    int*    deg     = (int*)alloc((size_t)NN * 4);
    int*    row_off = (int*)alloc((size_t)(NN + 1) * 4);
    int*    rank    = (int*)alloc((size_t)E * 4);
    int*    bsum    = (int*)alloc((size_t)NB_SCAN * 4);
    int*    bofs    = (int*)alloc((size_t)NB_SCAN * 4);
    int*    csr     = (int*)alloc((size_t)E * 4);
    __bf16* w1h     = (__bf16*)alloc((size_t)64 * KPAD * 2);
    __bf16* w1l     = (__bf16*)alloc((size_t)64 * KPAD * 2);
    __bf16* Hb0     = (__bf16*)alloc((size_t)NN * 32 * 2);
    __bf16* Hb1     = (__bf16*)alloc((size_t)NN * 32 * 2);
    __bf16* asadA   = (__bf16*)alloc((size_t)NN * 8 * 2);
    __bf16* asadB   = (__bf16*)alloc((size_t)NN * 8 * 2);
    float*  x2      = (float*)alloc((size_t)NN * 64 * 4);
    float*  h2a     = (float*)alloc((size_t)NN * 8 * 4);
    float*  ad2     = (float*)alloc((size_t)NN * 4);

    const int* src = ei;
    const int* dst = ei + E;

    k_prep   <<<64 + NB_SCAN, 256, 0, stream>>>(W1, w1h, w1l, deg);
    k_rank   <<<(E + 255) / 256, 256, 0, stream>>>(dst, deg, rank, E);
    k_scan1  <<<NB_SCAN, 256, 0, stream>>>(deg, bsum);
    k_scan2  <<<1, 256, 0, stream>>>(bsum, bofs);
    k_scan3  <<<NB_SCAN, 256, 0, stream>>>(deg, bofs, row_off);
    k_scatter<<<(E + 255) / 256, 256, 0, stream>>>(src, dst, rank, row_off, csr, E);
    k_gemm1  <<<(NN + 63) / 64, 256, 0, stream>>>(x, w1h, w1l, asrc1, adst1,
                                                  Hb0, Hb1, asadA, asadB);
    k_layer1p<<<NN / 4, 256, 0, stream>>>(asadA, Hb0, row_off, csr, b1,      x2, 0);
    k_layer1p<<<NN / 4, 256, 0, stream>>>(asadB, Hb1, row_off, csr, b1 + 32, x2, 32);
    k_gemm2  <<<(NN + 255) / 256, 256, 0, stream>>>(x2, W2, asrc2, adst2, h2a, ad2);
    k_layer2 <<<(NN + 31) / 32, 256, 0, stream>>>(ad2, h2a, row_off, csr, b2, out);
}

// Round 11
// 348.149 us; speedup vs baseline: 2.1551x; 1.0090x over previous
//
#include <hip/hip_runtime.h>
#include <hip/hip_bf16.h>

static constexpr int NN      = 50000;
static constexpr int FIN     = 1433;
static constexpr int KPAD    = 1440;            // 45 * 32
static constexpr int NB_SCAN = (NN + 255) / 256; // 196
static constexpr int L1B     = NN / 4;           // 12500 blocks per layer-1 pass

typedef __bf16 bf16x8 __attribute__((ext_vector_type(8)));
typedef float  f32x4  __attribute__((ext_vector_type(4)));

__device__ __forceinline__ float leaky02(float v){ return v >= 0.f ? v : 0.2f * v; }
__device__ __forceinline__ float bflo(unsigned u){ return __uint_as_float(u << 16); }
__device__ __forceinline__ float bfhi(unsigned u){ return __uint_as_float(u & 0xffff0000u); }

// async global->LDS, 4 bytes/lane: lane l writes lds_base + l*4
__device__ __forceinline__ void gld_lds4(const float* g, float* l){
    __builtin_amdgcn_global_load_lds(
        (const __attribute__((address_space(1))) unsigned int*)g,
        (__attribute__((address_space(3))) unsigned int*)l, 4, 0, 0);
}

// ---------------- prep: W1 transpose/split + deg zero, one dispatch ----------------
__global__ __launch_bounds__(256) void k_prep(const float* __restrict__ W1,
                                              __bf16* __restrict__ w1h, __bf16* __restrict__ w1l,
                                              int* __restrict__ deg){
    int bid = blockIdx.x;
    if (bid < 64){
        int c = bid;                          // output column
        for (int k = threadIdx.x; k < KPAD; k += 256){
            float v = (k < FIN) ? W1[(size_t)k * 64 + c] : 0.f;
            __bf16 hi = (__bf16)v;
            w1h[(size_t)c * KPAD + k] = hi;
            w1l[(size_t)c * KPAD + k] = (__bf16)(v - (float)hi);
        }
    } else {
        int i = (bid - 64) * 256 + threadIdx.x;
        if (i < NN) deg[i] = 0;
    }
}

// ---------------- CSR build ----------------
// rank: 4 edges/thread (stride 256), atomics issued as an independent group for ILP.
__global__ __launch_bounds__(256) void k_rank(const int* __restrict__ dst, int* __restrict__ deg,
                                              int* __restrict__ rank, int E){
    int base = blockIdx.x * 1024 + threadIdx.x;
    int d[4]; bool v[4];
    #pragma unroll
    for (int i = 0; i < 4; ++i){
        int e = base + i * 256;
        v[i] = e < E;
        d[i] = v[i] ? dst[e] : 0;
    }
    int r[4];
    #pragma unroll
    for (int i = 0; i < 4; ++i)
        if (v[i]) r[i] = atomicAdd(&deg[d[i]], 1);
    #pragma unroll
    for (int i = 0; i < 4; ++i)
        if (v[i]) rank[base + i * 256] = r[i];
}

__global__ __launch_bounds__(256) void k_scan1(const int* __restrict__ deg, int* __restrict__ bsum){
    __shared__ int red[256];
    int i = blockIdx.x * 256 + threadIdx.x;
    red[threadIdx.x] = (i < NN) ? deg[i] : 0;
    __syncthreads();
    for (int off = 128; off > 0; off >>= 1){
        if (threadIdx.x < off) red[threadIdx.x] += red[threadIdx.x + off];
        __syncthreads();
    }
    if (threadIdx.x == 0) bsum[blockIdx.x] = red[0];
}

// scan3 with scan2 folded in: each block tree-sums bsum[0..bid) itself (196 values).
__global__ __launch_bounds__(256) void k_scan3(const int* __restrict__ deg, const int* __restrict__ bsum,
                                               int* __restrict__ row_off){
    __shared__ int s[256];
    int t = threadIdx.x;
    int i = blockIdx.x * 256 + t;
    // phase 1: block offset = sum of bsum[0..bid)   (t < bid <= 195 < 256)
    s[t] = (t < blockIdx.x) ? bsum[t] : 0;
    __syncthreads();
    for (int off = 128; off > 0; off >>= 1){
        if (t < off) s[t] += s[t + off];
        __syncthreads();
    }
    int bofs = s[0];
    __syncthreads();
    // phase 2: intra-block inclusive scan of deg
    int d = (i < NN) ? deg[i] : 0;
    s[t] = d;
    __syncthreads();
    for (int off = 1; off < 256; off <<= 1){
        int v = s[t];
        int a = (t >= off) ? s[t - off] : 0;
        __syncthreads();
        s[t] = v + a;
        __syncthreads();
    }
    int excl = s[t] - d + bofs;
    if (i < NN){
        row_off[i] = excl;
        if (i == NN - 1) row_off[NN] = excl + d;
    }
}

// atomic-free scatter using precomputed rank; 4 edges/thread for gather/store ILP.
__global__ __launch_bounds__(256) void k_scatter(const int* __restrict__ src, const int* __restrict__ dst,
                                                 const int* __restrict__ rank, const int* __restrict__ row_off,
                                                 int* __restrict__ csr, int E){
    int base = blockIdx.x * 1024 + threadIdx.x;
    int d[4], r[4], sv[4]; bool v[4];
    #pragma unroll
    for (int i = 0; i < 4; ++i){
        int e = base + i * 256;
        v[i] = e < E;
        if (v[i]){ d[i] = dst[e]; r[i] = rank[e]; sv[i] = src[e]; }
    }
    int ro[4];
    #pragma unroll
    for (int i = 0; i < 4; ++i)
        if (v[i]) ro[i] = row_off[d[i]];
    #pragma unroll
    for (int i = 0; i < 4; ++i)
        if (v[i]) csr[ro[i] + r[i]] = sv[i];
}

// ---------------- GEMM1: H = x @ W1 (+ fused alpha1), head-split outputs ----------------
// 64 rows/block, 4 waves; wave w owns cols w*16..w*16+15.
// 3-phase pipeline: (1) async f32 stage into As (gld_lds4), (2) cooperative one-time
// bf16 hi/lo convert As -> AH/AL planes, (3) compute reads AH/AL with zero convert VALU.
__global__ __launch_bounds__(256, 4) void k_gemm1(const float* __restrict__ x,
    const __bf16* __restrict__ w1h, const __bf16* __restrict__ w1l,
    const float* __restrict__ a_s, const float* __restrict__ a_d,
    __bf16* __restrict__ Hb0, __bf16* __restrict__ Hb1,
    __bf16* __restrict__ asadA, __bf16* __restrict__ asadB)
{
    __shared__ float  As[64 * 68];           // 17.4 KB f32 staging (stride 68)
    __shared__ __bf16 AH[64 * 72];           // 9.2 KB hi plane (stride 72)
    __shared__ __bf16 AL[64 * 72];           // 9.2 KB lo plane
    const int tid  = threadIdx.x;
    const int w    = tid >> 6;
    const int lane = tid & 63;
    const int lr   = lane & 15;
    const int lk   = lane >> 4;
    const int rbase = blockIdx.x * 64;
    const int cr = tid >> 2;
    const int cg = (tid & 3) * 16;

    unsigned rowoff[16];
    #pragma unroll
    for (int i = 0; i < 16; ++i){
        int rg = rbase + w * 16 + i; if (rg >= NN) rg = NN - 1;
        rowoff[i] = (unsigned)rg * (unsigned)FIN + (unsigned)lane;
    }

    const __bf16* bh_p = w1h + (size_t)(w * 16 + lr) * KPAD + lk * 8;
    const __bf16* bl_p = w1l + (size_t)(w * 16 + lr) * KPAD + lk * 8;

    f32x4 acc[4] = {{0,0,0,0},{0,0,0,0},{0,0,0,0},{0,0,0,0}};

    #pragma unroll
    for (int i = 0; i < 16; ++i)
        gld_lds4(x + rowoff[i], &As[(w * 16 + i) * 68]);
    __syncthreads();

    for (int kb = 0; kb < 22; ++kb){
        {   // phase 2: one-time convert As -> AH/AL
            const float* rp = &As[cr * 68 + cg];
            f32x4 v[4];
            #pragma unroll
            for (int j = 0; j < 4; ++j) v[j] = *(const f32x4*)(rp + j * 4);
            bf16x8 hv0, hv1, lv0, lv1;
            #pragma unroll
            for (int j = 0; j < 2; ++j){
                #pragma unroll
                for (int e = 0; e < 4; ++e){
                    float a0 = v[2 * j][e], a1 = v[2 * j + 1][e];
                    __bf16 h0 = (__bf16)a0, h1 = (__bf16)a1;
                    if (j == 0){ hv0[e] = h0; hv0[e + 4] = h1;
                                 lv0[e] = (__bf16)(a0 - (float)h0);
                                 lv0[e + 4] = (__bf16)(a1 - (float)h1); }
                    else       { hv1[e] = h0; hv1[e + 4] = h1;
                                 lv1[e] = (__bf16)(a0 - (float)h0);
                                 lv1[e + 4] = (__bf16)(a1 - (float)h1); }
                }
            }
            *(bf16x8*)&AH[cr * 72 + cg]     = hv0;
            *(bf16x8*)&AH[cr * 72 + cg + 8] = hv1;
            *(bf16x8*)&AL[cr * 72 + cg]     = lv0;
            *(bf16x8*)&AL[cr * 72 + cg + 8] = lv1;
        }
        __syncthreads();

        if (kb < 21){   // phase 1: async stage kb+1 into As
            const float* gsrc = x + (kb + 1) * 64;
            #pragma unroll
            for (int i = 0; i < 16; ++i)
                gld_lds4(gsrc + rowoff[i], &As[(w * 16 + i) * 68]);
        }

        // phase 3: compute from AH/AL
        const int kA = kb * 64;
        bf16x8 bh0 = *(const bf16x8*)(bh_p + kA);
        bf16x8 bl0 = *(const bf16x8*)(bl_p + kA);
        bf16x8 bh1 = *(const bf16x8*)(bh_p + kA + 32);
        bf16x8 bl1 = *(const bf16x8*)(bl_p + kA + 32);
        #pragma unroll
        for (int ks = 0; ks < 2; ++ks){
            bf16x8 bh = ks ? bh1 : bh0;
            bf16x8 bl = ks ? bl1 : bl0;
            #pragma unroll
            for (int t = 0; t < 4; ++t){
                const int ao = (t * 16 + lr) * 72 + ks * 32 + lk * 8;
                bf16x8 ah = *(const bf16x8*)&AH[ao];
                bf16x8 al = *(const bf16x8*)&AL[ao];
                acc[t] = __builtin_amdgcn_mfma_f32_16x16x32_bf16(ah, bh, acc[t], 0, 0, 0);
                acc[t] = __builtin_amdgcn_mfma_f32_16x16x32_bf16(al, bh, acc[t], 0, 0, 0);
                acc[t] = __builtin_amdgcn_mfma_f32_16x16x32_bf16(ah, bl, acc[t], 0, 0, 0);
            }
        }
        __syncthreads();
    }

    // peeled masked tail: k 1408..1439 (valid < 1433), direct loads
    {
        bf16x8 bh = *(const bf16x8*)(bh_p + 1408);
        bf16x8 bl = *(const bf16x8*)(bl_p + 1408);
        #pragma unroll
        for (int t = 0; t < 4; ++t){
            int rg = rbase + t * 16 + lr; if (rg >= NN) rg = NN - 1;
            const float* xr = x + (size_t)rg * FIN;
            bf16x8 ah, al;
            #pragma unroll
            for (int e = 0; e < 8; ++e){
                int k = 1408 + lk * 8 + e;
                float v = (k < FIN) ? xr[k] : 0.f;
                __bf16 h = (__bf16)v;
                ah[e] = h; al[e] = (__bf16)(v - (float)h);
            }
            acc[t] = __builtin_amdgcn_mfma_f32_16x16x32_bf16(ah, bh, acc[t], 0, 0, 0);
            acc[t] = __builtin_amdgcn_mfma_f32_16x16x32_bf16(al, bh, acc[t], 0, 0, 0);
            acc[t] = __builtin_amdgcn_mfma_f32_16x16x32_bf16(ah, bl, acc[t], 0, 0, 0);
        }
    }

    // epilogue 1: H tile -> LDS (As, f32) + bf16 head-half stores
    __syncthreads();
    const int col = w * 16 + lr;
    __bf16* hbp = (col < 32) ? Hb0 : Hb1;
    const int cc = col & 31;
    #pragma unroll
    for (int t = 0; t < 4; ++t){
        #pragma unroll
        for (int r = 0; r < 4; ++r){
            int rib = t * 16 + lk * 4 + r;
            float v = acc[t][r];
            As[rib * 68 + col] = v;
            int row = rbase + rib;
            if (row < NN) hbp[(size_t)row * 32 + cc] = (__bf16)v;
        }
    }
    __syncthreads();
    // epilogue 2: fused alpha1 -> bf16 asad records
    #pragma unroll
    for (int it = 0; it < 2; ++it){
        int task = tid + it * 256;
        int row  = task >> 3;
        int hh   = task & 7;
        int grow = rbase + row;
        if (grow < NN){
            const float* hr = &As[row * 68 + hh * 8];
            float s = 0.f, dd = 0.f;
            #pragma unroll
            for (int c = 0; c < 8; ++c){
                float v = hr[c];
                s  = fmaf(v, a_s[hh * 8 + c], s);
                dd = fmaf(v, a_d[hh * 8 + c], dd);
            }
            if (hh < 4){
                asadA[(size_t)grow * 8 + hh]     = (__bf16)s;
                asadA[(size_t)grow * 8 + 4 + hh] = (__bf16)dd;
            } else {
                asadB[(size_t)grow * 8 + (hh - 4)]     = (__bf16)s;
                asadB[(size_t)grow * 8 + 4 + (hh - 4)] = (__bf16)dd;
            }
        }
    }
}

// ---------------- layer-1 edge pass, BOTH head-halves in one dispatch ----------------
// bid < L1B -> pass A (cols 0..31); bid >= L1B -> pass B (cols 32..63).
// wave = 1 dst node; lane l = (edge quarter q=l>>4) x (channel pair sl=l&15).
__global__ __launch_bounds__(256, 8) void k_layer1(const __bf16* __restrict__ asadA,
    const __bf16* __restrict__ asadB, const __bf16* __restrict__ Hb0, const __bf16* __restrict__ Hb1,
    const int* __restrict__ row_off, const int* __restrict__ csr,
    const float* __restrict__ b1, float* __restrict__ x2)
{
    const int bid  = blockIdx.x;
    const int pass = (bid >= L1B);
    const int nb4  = pass ? bid - L1B : bid;
    const __bf16* asadP = pass ? asadB : asadA;
    const __bf16* HbP   = pass ? Hb1 : Hb0;
    const float*  b1P   = b1 + pass * 32;
    const int colbase   = pass * 32;

    const int d  = nb4 * 4 + (threadIdx.x >> 6);
    const int l  = threadIdx.x & 63;
    const int q  = l >> 4;           // edge slot within batch (0..3)
    const int sl = l & 15;           // channel pair index
    const int c0 = 2 * sl;
    const int h  = sl >> 2;          // head for both channels of the pair
    const float adv = (float)asadP[(size_t)d * 8 + 4 + h];

    float den = 0.f, a0 = 0.f, a1 = 0.f;
    if (q == 0){
        float as_d = (float)asadP[(size_t)d * 8 + h];
        float p0 = __expf(leaky02(as_d + adv) - 20.f);   // fixed-offset softmax (e << 20)
        unsigned hw = *(const unsigned*)&HbP[(size_t)d * 32 + c0];
        den = p0;
        a0 = p0 * bflo(hw);
        a1 = p0 * bfhi(hw);
    }

    const int beg = row_off[d], end = row_off[d + 1];
    const int nb = (end - beg + 7) >> 3;     // 8-edge batches
    int csrv = 0;
    if (nb > 0){
        int idx = beg + (l & 7); if (idx >= end) idx = end - 1;
        csrv = __builtin_nontemporal_load(csr + idx);
    }
    for (int b = 0; b < nb; ++b){
        const int base = beg + b * 8;
        int ncsr = 0;
        if (b + 1 < nb){
            int idx = base + 8 + (l & 7); if (idx >= end) idx = end - 1;
            ncsr = __builtin_nontemporal_load(csr + idx);
        }
        int s0 = __shfl(csrv, q, 8);
        int s1 = __shfl(csrv, 4 + q, 8);
        const bool v0 = (base + q) < end;
        const bool v1 = (base + 4 + q) < end;
        unsigned hw0 = 0, hw1 = 0; float av0 = 0.f, av1 = 0.f;
        if (v0){ hw0 = *(const unsigned*)&HbP[(size_t)s0 * 32 + c0];
                 av0 = (float)asadP[(size_t)s0 * 8 + h]; }
        if (v1){ hw1 = *(const unsigned*)&HbP[(size_t)s1 * 32 + c0];
                 av1 = (float)asadP[(size_t)s1 * 8 + h]; }
        if (v0){
            float p = __expf(leaky02(av0 + adv) - 20.f);
            den += p; a0 = fmaf(p, bflo(hw0), a0); a1 = fmaf(p, bfhi(hw0), a1);
        }
        if (v1){
            float p = __expf(leaky02(av1 + adv) - 20.f);
            den += p; a0 = fmaf(p, bflo(hw1), a0); a1 = fmaf(p, bfhi(hw1), a1);
        }
        csrv = ncsr;
    }

    // cross-quarter reduction (quarters processed disjoint edges)
    a0  += __shfl_xor(a0, 16, 64);  a0  += __shfl_xor(a0, 32, 64);
    a1  += __shfl_xor(a1, 16, 64);  a1  += __shfl_xor(a1, 32, 64);
    den += __shfl_xor(den, 16, 64); den += __shfl_xor(den, 32, 64);

    if (q == 0){
        float o0 = a0 / den + b1P[c0];
        float o1 = a1 / den + b1P[c0 + 1];
        o0 = (o0 > 0.f) ? o0 : (__expf(o0) - 1.f);       // ELU fused
        o1 = (o1 > 0.f) ? o1 : (__expf(o1) - 1.f);
        float2 ov = make_float2(o0, o1);
        *(float2*)&x2[(size_t)d * 64 + colbase + c0] = ov;
    }
}

// ---------------- GEMM2 + attention logits, layer 2 ----------------
// h2a[n][8]: [0..6] = h2 channels, [7] = as2 (packed record, one gather/edge later)
__global__ __launch_bounds__(256) void k_gemm2(const float* __restrict__ x2, const float* __restrict__ W2,
    const float* __restrict__ aw_in, const float* __restrict__ dw_in,
    float* __restrict__ h2a, float* __restrict__ ad2)
{
    __shared__ float w2s[448];
    __shared__ float aw[7], dw[7];
    int tid = threadIdx.x;
    for (int i = tid; i < 448; i += 256) w2s[i] = W2[i];
    if (tid < 7){ aw[tid] = aw_in[tid]; dw[tid] = dw_in[tid]; }
    __syncthreads();
    int n = blockIdx.x * 256 + tid;
    if (n >= NN) return;
    const float4* xp = (const float4*)(x2 + (size_t)n * 64);
    float acc[7] = {0.f,0.f,0.f,0.f,0.f,0.f,0.f};
    #pragma unroll
    for (int q = 0; q < 16; ++q){
        float4 v = xp[q];
        float vv[4] = {v.x, v.y, v.z, v.w};
        #pragma unroll
        for (int u = 0; u < 4; ++u){
            int k = q * 4 + u;
            #pragma unroll
            for (int c = 0; c < 7; ++c) acc[c] = fmaf(vv[u], w2s[k * 7 + c], acc[c]);
        }
    }
    float s = 0.f, d = 0.f;
    #pragma unroll
    for (int c = 0; c < 7; ++c){ s = fmaf(acc[c], aw[c], s); d = fmaf(acc[c], dw[c], d); }
    float* hp = h2a + (size_t)n * 8;
    #pragma unroll
    for (int c = 0; c < 7; ++c) hp[c] = acc[c];
    hp[7] = s;                                  // as2 packed into the record
    ad2[n] = d;
}

// ---------------- layer-2 edge pass + bias + log_softmax: 8 lanes/node, 16-edge batches ----------------
__global__ __launch_bounds__(256) void k_layer2(const float* __restrict__ ad2,
    const float* __restrict__ h2a, const int* __restrict__ row_off, const int* __restrict__ csr,
    const float* __restrict__ b2, float* __restrict__ out)
{
    int tid  = threadIdx.x;
    int node = blockIdx.x * 32 + (tid >> 3);
    int c    = tid & 7;
    int lane = tid & 63;
    int gb   = lane & ~7;                        // 8-lane group base within wave
    if (node >= NN) return;
    float adv   = ad2[node];
    float vself = h2a[(size_t)node * 8 + c];
    float as_n  = __shfl(vself, gb + 7, 64);
    float e0 = leaky02(as_n + adv);
    float p0 = __expf(e0 - 20.f);
    float den = p0;
    float acc = p0 * vself;                      // c==7 lane accumulates garbage; unused
    int beg = row_off[node], end = row_off[node + 1];
    for (int base = beg; base < end; base += 16){
        int cnt = end - base; if (cnt > 16) cnt = 16;
        int j1  = 8 + c;
        int cs0 = csr[base + (c  < cnt ? c  : cnt - 1)];
        int cs1 = csr[base + (j1 < cnt ? j1 : cnt - 1)];
        float val[16];
        #pragma unroll
        for (int t = 0; t < 16; ++t){
            if (t < cnt){
                int s = (t < 8) ? __shfl(cs0, gb + t, 64) : __shfl(cs1, gb + t - 8, 64);
                val[t] = h2a[(size_t)s * 8 + c];
            }
        }
        #pragma unroll
        for (int t = 0; t < 16; ++t){
            if (t < cnt){
                float as_s = __shfl(val[t], gb + 7, 64);
                float e = leaky02(as_s + adv);
                float p = __expf(e - 20.f);
                den += p;
                acc  = fmaf(p, val[t], acc);
            }
        }
    }
    float v = (c < 7) ? (acc / den + b2[c]) : -1e30f;
    float m = v;
    m = fmaxf(m, __shfl_xor(m, 1, 64));
    m = fmaxf(m, __shfl_xor(m, 2, 64));
    m = fmaxf(m, __shfl_xor(m, 4, 64));
    float ex = (c < 7) ? __expf(v - m) : 0.f;
    float s7 = ex;
    s7 += __shfl_xor(s7, 1, 64);
    s7 += __shfl_xor(s7, 2, 64);
    s7 += __shfl_xor(s7, 4, 64);
    if (c < 7) out[(size_t)node * 7 + c] = v - m - __logf(s7);
}

// ---------------- launcher ----------------
extern "C" void kernel_launch(void* const* d_in, const int* in_sizes, int n_in,
                              void* d_out, int out_size, void* d_ws, size_t ws_size,
                              hipStream_t stream)
{
    (void)n_in; (void)out_size; (void)ws_size;
    const float* x      = (const float*)d_in[0];
    const int*   ei     = (const int*)d_in[1];
    const int    E      = in_sizes[1] / 2;
    const float* W1     = (const float*)d_in[2];
    const float* asrc1  = (const float*)d_in[3];
    const float* adst1  = (const float*)d_in[4];
    const float* b1     = (const float*)d_in[5];
    const float* W2     = (const float*)d_in[6];
    const float* asrc2  = (const float*)d_in[7];
    const float* adst2  = (const float*)d_in[8];
    const float* b2     = (const float*)d_in[9];
    float* out = (float*)d_out;

    char* p = (char*)d_ws;
    auto alloc = [&](size_t bytes) -> void* {
        void* r = (void*)p;
        p += (bytes + 255) & ~(size_t)255;
        return r;
    };
    int*    deg     = (int*)alloc((size_t)NN * 4);
    int*    row_off = (int*)alloc((size_t)(NN + 1) * 4);
    int*    rank    = (int*)alloc((size_t)E * 4);
    int*    bsum    = (int*)alloc((size_t)NB_SCAN * 4);
    int*    csr     = (int*)alloc((size_t)E * 4);
    __bf16* w1h     = (__bf16*)alloc((size_t)64 * KPAD * 2);
    __bf16* w1l     = (__bf16*)alloc((size_t)64 * KPAD * 2);
    __bf16* Hb0     = (__bf16*)alloc((size_t)NN * 32 * 2);
    __bf16* Hb1     = (__bf16*)alloc((size_t)NN * 32 * 2);
    __bf16* asadA   = (__bf16*)alloc((size_t)NN * 8 * 2);
    __bf16* asadB   = (__bf16*)alloc((size_t)NN * 8 * 2);
    float*  x2      = (float*)alloc((size_t)NN * 64 * 4);
    float*  h2a     = (float*)alloc((size_t)NN * 8 * 4);
    float*  ad2     = (float*)alloc((size_t)NN * 4);

    const int* src = ei;
    const int* dst = ei + E;

    k_prep   <<<64 + NB_SCAN, 256, 0, stream>>>(W1, w1h, w1l, deg);
    k_rank   <<<(E + 1023) / 1024, 256, 0, stream>>>(dst, deg, rank, E);
    k_scan1  <<<NB_SCAN, 256, 0, stream>>>(deg, bsum);
    k_scan3  <<<NB_SCAN, 256, 0, stream>>>(deg, bsum, row_off);
    k_scatter<<<(E + 1023) / 1024, 256, 0, stream>>>(src, dst, rank, row_off, csr, E);
    k_gemm1  <<<(NN + 63) / 64, 256, 0, stream>>>(x, w1h, w1l, asrc1, adst1,
                                                  Hb0, Hb1, asadA, asadB);
    k_layer1 <<<2 * L1B, 256, 0, stream>>>(asadA, asadB, Hb0, Hb1, row_off, csr, b1, x2);
    k_gemm2  <<<(NN + 255) / 256, 256, 0, stream>>>(x2, W2, asrc2, adst2, h2a, ad2);
    k_layer2 <<<(NN + 31) / 32, 256, 0, stream>>>(ad2, h2a, row_off, csr, b2, out);
}

// Round 12
// 328.515 us; speedup vs baseline: 2.2839x; 1.0598x over previous
//
#include <hip/hip_runtime.h>
#include <hip/hip_bf16.h>

static constexpr int NN      = 50000;
static constexpr int FIN     = 1433;
static constexpr int KPAD    = 1440;            // 45 * 32
static constexpr int NB_SCAN = (NN + 255) / 256; // 196
static constexpr int L1B     = NN / 4;           // 12500 blocks per layer-1 pass

typedef __bf16 bf16x8 __attribute__((ext_vector_type(8)));
typedef float  f32x4  __attribute__((ext_vector_type(4)));

__device__ __forceinline__ float leaky02(float v){ return v >= 0.f ? v : 0.2f * v; }
__device__ __forceinline__ float bflo(unsigned u){ return __uint_as_float(u << 16); }
__device__ __forceinline__ float bfhi(unsigned u){ return __uint_as_float(u & 0xffff0000u); }

// async global->LDS, 4 bytes/lane: lane l writes lds_base + l*4
__device__ __forceinline__ void gld_lds4(const float* g, float* l){
    __builtin_amdgcn_global_load_lds(
        (const __attribute__((address_space(1))) unsigned int*)g,
        (__attribute__((address_space(3))) unsigned int*)l, 4, 0, 0);
}

// ---------------- prep: W1 transpose/split + deg zero, one dispatch ----------------
__global__ __launch_bounds__(256) void k_prep(const float* __restrict__ W1,
                                              __bf16* __restrict__ w1h, __bf16* __restrict__ w1l,
                                              int* __restrict__ deg){
    int bid = blockIdx.x;
    if (bid < 64){
        int c = bid;                          // output column
        for (int k = threadIdx.x; k < KPAD; k += 256){
            float v = (k < FIN) ? W1[(size_t)k * 64 + c] : 0.f;
            __bf16 hi = (__bf16)v;
            w1h[(size_t)c * KPAD + k] = hi;
            w1l[(size_t)c * KPAD + k] = (__bf16)(v - (float)hi);
        }
    } else {
        int i = (bid - 64) * 256 + threadIdx.x;
        if (i < NN) deg[i] = 0;
    }
}

// ---------------- CSR build ----------------
__global__ __launch_bounds__(256) void k_rank(const int* __restrict__ dst, int* __restrict__ deg,
                                              int* __restrict__ rank, int E){
    int base = blockIdx.x * 1024 + threadIdx.x;
    int d[4]; bool v[4];
    #pragma unroll
    for (int i = 0; i < 4; ++i){
        int e = base + i * 256;
        v[i] = e < E;
        d[i] = v[i] ? dst[e] : 0;
    }
    int r[4];
    #pragma unroll
    for (int i = 0; i < 4; ++i)
        if (v[i]) r[i] = atomicAdd(&deg[d[i]], 1);
    #pragma unroll
    for (int i = 0; i < 4; ++i)
        if (v[i]) rank[base + i * 256] = r[i];
}

__global__ __launch_bounds__(256) void k_scan1(const int* __restrict__ deg, int* __restrict__ bsum){
    __shared__ int red[256];
    int i = blockIdx.x * 256 + threadIdx.x;
    red[threadIdx.x] = (i < NN) ? deg[i] : 0;
    __syncthreads();
    for (int off = 128; off > 0; off >>= 1){
        if (threadIdx.x < off) red[threadIdx.x] += red[threadIdx.x + off];
        __syncthreads();
    }
    if (threadIdx.x == 0) bsum[blockIdx.x] = red[0];
}

// scan3 with scan2 folded in
__global__ __launch_bounds__(256) void k_scan3(const int* __restrict__ deg, const int* __restrict__ bsum,
                                               int* __restrict__ row_off){
    __shared__ int s[256];
    int t = threadIdx.x;
    int i = blockIdx.x * 256 + t;
    s[t] = (t < blockIdx.x) ? bsum[t] : 0;
    __syncthreads();
    for (int off = 128; off > 0; off >>= 1){
        if (t < off) s[t] += s[t + off];
        __syncthreads();
    }
    int bofs = s[0];
    __syncthreads();
    int d = (i < NN) ? deg[i] : 0;
    s[t] = d;
    __syncthreads();
    for (int off = 1; off < 256; off <<= 1){
        int v = s[t];
        int a = (t >= off) ? s[t - off] : 0;
        __syncthreads();
        s[t] = v + a;
        __syncthreads();
    }
    int excl = s[t] - d + bofs;
    if (i < NN){
        row_off[i] = excl;
        if (i == NN - 1) row_off[NN] = excl + d;
    }
}

__global__ __launch_bounds__(256) void k_scatter(const int* __restrict__ src, const int* __restrict__ dst,
                                                 const int* __restrict__ rank, const int* __restrict__ row_off,
                                                 int* __restrict__ csr, int E){
    int base = blockIdx.x * 1024 + threadIdx.x;
    int d[4], r[4], sv[4]; bool v[4];
    #pragma unroll
    for (int i = 0; i < 4; ++i){
        int e = base + i * 256;
        v[i] = e < E;
        if (v[i]){ d[i] = dst[e]; r[i] = rank[e]; sv[i] = src[e]; }
    }
    int ro[4];
    #pragma unroll
    for (int i = 0; i < 4; ++i)
        if (v[i]) ro[i] = row_off[d[i]];
    #pragma unroll
    for (int i = 0; i < 4; ++i)
        if (v[i]) csr[ro[i] + r[i]] = sv[i];
}

// ---------------- GEMM1: H = x @ W1 (+ fused alpha1), head-split outputs ----------------
__global__ __launch_bounds__(256, 4) void k_gemm1(const float* __restrict__ x,
    const __bf16* __restrict__ w1h, const __bf16* __restrict__ w1l,
    const float* __restrict__ a_s, const float* __restrict__ a_d,
    __bf16* __restrict__ Hb0, __bf16* __restrict__ Hb1,
    __bf16* __restrict__ asadA, __bf16* __restrict__ asadB)
{
    __shared__ float  As[64 * 68];           // 17.4 KB f32 staging (stride 68)
    __shared__ __bf16 AH[64 * 72];           // 9.2 KB hi plane (stride 72)
    __shared__ __bf16 AL[64 * 72];           // 9.2 KB lo plane
    const int tid  = threadIdx.x;
    const int w    = tid >> 6;
    const int lane = tid & 63;
    const int lr   = lane & 15;
    const int lk   = lane >> 4;
    const int rbase = blockIdx.x * 64;
    const int cr = tid >> 2;
    const int cg = (tid & 3) * 16;

    unsigned rowoff[16];
    #pragma unroll
    for (int i = 0; i < 16; ++i){
        int rg = rbase + w * 16 + i; if (rg >= NN) rg = NN - 1;
        rowoff[i] = (unsigned)rg * (unsigned)FIN + (unsigned)lane;
    }

    const __bf16* bh_p = w1h + (size_t)(w * 16 + lr) * KPAD + lk * 8;
    const __bf16* bl_p = w1l + (size_t)(w * 16 + lr) * KPAD + lk * 8;

    f32x4 acc[4] = {{0,0,0,0},{0,0,0,0},{0,0,0,0},{0,0,0,0}};

    #pragma unroll
    for (int i = 0; i < 16; ++i)
        gld_lds4(x + rowoff[i], &As[(w * 16 + i) * 68]);
    __syncthreads();

    for (int kb = 0; kb < 22; ++kb){
        {   // one-time convert As -> AH/AL
            const float* rp = &As[cr * 68 + cg];
            f32x4 v[4];
            #pragma unroll
            for (int j = 0; j < 4; ++j) v[j] = *(const f32x4*)(rp + j * 4);
            bf16x8 hv0, hv1, lv0, lv1;
            #pragma unroll
            for (int j = 0; j < 2; ++j){
                #pragma unroll
                for (int e = 0; e < 4; ++e){
                    float a0 = v[2 * j][e], a1 = v[2 * j + 1][e];
                    __bf16 h0 = (__bf16)a0, h1 = (__bf16)a1;
                    if (j == 0){ hv0[e] = h0; hv0[e + 4] = h1;
                                 lv0[e] = (__bf16)(a0 - (float)h0);
                                 lv0[e + 4] = (__bf16)(a1 - (float)h1); }
                    else       { hv1[e] = h0; hv1[e + 4] = h1;
                                 lv1[e] = (__bf16)(a0 - (float)h0);
                                 lv1[e + 4] = (__bf16)(a1 - (float)h1); }
                }
            }
            *(bf16x8*)&AH[cr * 72 + cg]     = hv0;
            *(bf16x8*)&AH[cr * 72 + cg + 8] = hv1;
            *(bf16x8*)&AL[cr * 72 + cg]     = lv0;
            *(bf16x8*)&AL[cr * 72 + cg + 8] = lv1;
        }
        __syncthreads();

        if (kb < 21){
            const float* gsrc = x + (kb + 1) * 64;
            #pragma unroll
            for (int i = 0; i < 16; ++i)
                gld_lds4(gsrc + rowoff[i], &As[(w * 16 + i) * 68]);
        }

        const int kA = kb * 64;
        bf16x8 bh0 = *(const bf16x8*)(bh_p + kA);
        bf16x8 bl0 = *(const bf16x8*)(bl_p + kA);
        bf16x8 bh1 = *(const bf16x8*)(bh_p + kA + 32);
        bf16x8 bl1 = *(const bf16x8*)(bl_p + kA + 32);
        #pragma unroll
        for (int ks = 0; ks < 2; ++ks){
            bf16x8 bh = ks ? bh1 : bh0;
            bf16x8 bl = ks ? bl1 : bl0;
            #pragma unroll
            for (int t = 0; t < 4; ++t){
                const int ao = (t * 16 + lr) * 72 + ks * 32 + lk * 8;
                bf16x8 ah = *(const bf16x8*)&AH[ao];
                bf16x8 al = *(const bf16x8*)&AL[ao];
                acc[t] = __builtin_amdgcn_mfma_f32_16x16x32_bf16(ah, bh, acc[t], 0, 0, 0);
                acc[t] = __builtin_amdgcn_mfma_f32_16x16x32_bf16(al, bh, acc[t], 0, 0, 0);
                acc[t] = __builtin_amdgcn_mfma_f32_16x16x32_bf16(ah, bl, acc[t], 0, 0, 0);
            }
        }
        __syncthreads();
    }

    // peeled masked tail: k 1408..1439 (valid < 1433)
    {
        bf16x8 bh = *(const bf16x8*)(bh_p + 1408);
        bf16x8 bl = *(const bf16x8*)(bl_p + 1408);
        #pragma unroll
        for (int t = 0; t < 4; ++t){
            int rg = rbase + t * 16 + lr; if (rg >= NN) rg = NN - 1;
            const float* xr = x + (size_t)rg * FIN;
            bf16x8 ah, al;
            #pragma unroll
            for (int e = 0; e < 8; ++e){
                int k = 1408 + lk * 8 + e;
                float v = (k < FIN) ? xr[k] : 0.f;
                __bf16 h = (__bf16)v;
                ah[e] = h; al[e] = (__bf16)(v - (float)h);
            }
            acc[t] = __builtin_amdgcn_mfma_f32_16x16x32_bf16(ah, bh, acc[t], 0, 0, 0);
            acc[t] = __builtin_amdgcn_mfma_f32_16x16x32_bf16(al, bh, acc[t], 0, 0, 0);
            acc[t] = __builtin_amdgcn_mfma_f32_16x16x32_bf16(ah, bl, acc[t], 0, 0, 0);
        }
    }

    // epilogue 1: H tile -> LDS (As, f32) + bf16 head-half stores
    __syncthreads();
    const int col = w * 16 + lr;
    __bf16* hbp = (col < 32) ? Hb0 : Hb1;
    const int cc = col & 31;
    #pragma unroll
    for (int t = 0; t < 4; ++t){
        #pragma unroll
        for (int r = 0; r < 4; ++r){
            int rib = t * 16 + lk * 4 + r;
            float v = acc[t][r];
            As[rib * 68 + col] = v;
            int row = rbase + rib;
            if (row < NN) hbp[(size_t)row * 32 + cc] = (__bf16)v;
        }
    }
    __syncthreads();
    // epilogue 2: fused alpha1 -> bf16 asad records
    #pragma unroll
    for (int it = 0; it < 2; ++it){
        int task = tid + it * 256;
        int row  = task >> 3;
        int hh   = task & 7;
        int grow = rbase + row;
        if (grow < NN){
            const float* hr = &As[row * 68 + hh * 8];
            float s = 0.f, dd = 0.f;
            #pragma unroll
            for (int c = 0; c < 8; ++c){
                float v = hr[c];
                s  = fmaf(v, a_s[hh * 8 + c], s);
                dd = fmaf(v, a_d[hh * 8 + c], dd);
            }
            if (hh < 4){
                asadA[(size_t)grow * 8 + hh]     = (__bf16)s;
                asadA[(size_t)grow * 8 + 4 + hh] = (__bf16)dd;
            } else {
                asadB[(size_t)grow * 8 + (hh - 4)]     = (__bf16)s;
                asadB[(size_t)grow * 8 + 4 + (hh - 4)] = (__bf16)dd;
            }
        }
    }
}

// ---------------- layer-1 edge pass, both head-halves in one dispatch ----------------
// lane l = (edge slot e8 = l>>3) x (channel chunk c8 = l&7 -> 4 channels, uint2).
// Per 8-edge batch: 1 csr + 1 uint2 H-row + 1 as load = 3 wave-VMEM (0.38/edge).
__global__ __launch_bounds__(256, 8) void k_layer1(const __bf16* __restrict__ asadA,
    const __bf16* __restrict__ asadB, const __bf16* __restrict__ Hb0, const __bf16* __restrict__ Hb1,
    const int* __restrict__ row_off, const int* __restrict__ csr,
    const float* __restrict__ b1, float* __restrict__ x2)
{
    const int bid  = blockIdx.x;
    const int pass = (bid >= L1B);
    const int nb4  = pass ? bid - L1B : bid;
    const __bf16* asadP = pass ? asadB : asadA;
    const __bf16* HbP   = pass ? Hb1 : Hb0;
    const float*  b1P   = b1 + pass * 32;
    const int colbase   = pass * 32;

    const int d  = nb4 * 4 + (threadIdx.x >> 6);
    const int l  = threadIdx.x & 63;
    const int e8 = l >> 3;           // edge slot (0..7)
    const int c8 = l & 7;            // channel chunk (4 channels)
    const int c0 = c8 * 4;
    const int h  = c8 >> 1;          // head for this chunk
    const float adv = (float)asadP[(size_t)d * 8 + 4 + h];

    float den = 0.f, a0 = 0.f, a1 = 0.f, a2 = 0.f, a3 = 0.f;
    if (e8 == 0){
        float as_d = (float)asadP[(size_t)d * 8 + h];
        float p0 = __expf(leaky02(as_d + adv) - 20.f);   // fixed-offset softmax (e << 20)
        uint2 hw = *(const uint2*)&HbP[(size_t)d * 32 + c0];
        den = p0;
        a0 = p0 * bflo(hw.x); a1 = p0 * bfhi(hw.x);
        a2 = p0 * bflo(hw.y); a3 = p0 * bfhi(hw.y);
    }

    const int beg = row_off[d], end = row_off[d + 1];
    const int nb = (end - beg + 7) >> 3;     // 8-edge batches
    int csrv = 0;
    if (nb > 0){
        int idx = beg + c8; if (idx >= end) idx = end - 1;    // (l&7) pattern
        csrv = __builtin_nontemporal_load(csr + idx);
    }
    for (int b = 0; b < nb; ++b){
        const int base = beg + b * 8;
        int ncsr = 0;
        if (b + 1 < nb){
            int idx = base + 8 + c8; if (idx >= end) idx = end - 1;
            ncsr = __builtin_nontemporal_load(csr + idx);
        }
        int s = __shfl(csrv, e8, 8);             // edge (base+e8)'s src, broadcast to its 8 lanes
        const bool val = (base + e8) < end;
        uint2 hw = make_uint2(0u, 0u); float av = 0.f;
        if (val){
            hw = *(const uint2*)&HbP[(size_t)s * 32 + c0];
            av = (float)asadP[(size_t)s * 8 + h];
        }
        if (val){
            float p = __expf(leaky02(av + adv) - 20.f);
            den += p;
            a0 = fmaf(p, bflo(hw.x), a0); a1 = fmaf(p, bfhi(hw.x), a1);
            a2 = fmaf(p, bflo(hw.y), a2); a3 = fmaf(p, bfhi(hw.y), a3);
        }
        csrv = ncsr;
    }

    // reduce over edge slots (lane bits 3..5); each lane's partials cover disjoint edges
    #pragma unroll
    for (int m = 8; m <= 32; m <<= 1){
        a0  += __shfl_xor(a0,  m, 64);
        a1  += __shfl_xor(a1,  m, 64);
        a2  += __shfl_xor(a2,  m, 64);
        a3  += __shfl_xor(a3,  m, 64);
        den += __shfl_xor(den, m, 64);
    }

    if (e8 == 0){
        float inv = 1.f / den;
        float o[4] = { a0 * inv + b1P[c0],     a1 * inv + b1P[c0 + 1],
                       a2 * inv + b1P[c0 + 2], a3 * inv + b1P[c0 + 3] };
        #pragma unroll
        for (int j = 0; j < 4; ++j) o[j] = (o[j] > 0.f) ? o[j] : (__expf(o[j]) - 1.f);  // ELU
        float4 ov = make_float4(o[0], o[1], o[2], o[3]);
        *(float4*)&x2[(size_t)d * 64 + colbase + c0] = ov;
    }
}

// ---------------- GEMM2 + attention logits, layer 2 ----------------
__global__ __launch_bounds__(256) void k_gemm2(const float* __restrict__ x2, const float* __restrict__ W2,
    const float* __restrict__ aw_in, const float* __restrict__ dw_in,
    float* __restrict__ h2a, float* __restrict__ ad2)
{
    __shared__ float w2s[448];
    __shared__ float aw[7], dw[7];
    int tid = threadIdx.x;
    for (int i = tid; i < 448; i += 256) w2s[i] = W2[i];
    if (tid < 7){ aw[tid] = aw_in[tid]; dw[tid] = dw_in[tid]; }
    __syncthreads();
    int n = blockIdx.x * 256 + tid;
    if (n >= NN) return;
    const float4* xp = (const float4*)(x2 + (size_t)n * 64);
    float acc[7] = {0.f,0.f,0.f,0.f,0.f,0.f,0.f};
    #pragma unroll
    for (int q = 0; q < 16; ++q){
        float4 v = xp[q];
        float vv[4] = {v.x, v.y, v.z, v.w};
        #pragma unroll
        for (int u = 0; u < 4; ++u){
            int k = q * 4 + u;
            #pragma unroll
            for (int c = 0; c < 7; ++c) acc[c] = fmaf(vv[u], w2s[k * 7 + c], acc[c]);
        }
    }
    float s = 0.f, d = 0.f;
    #pragma unroll
    for (int c = 0; c < 7; ++c){ s = fmaf(acc[c], aw[c], s); d = fmaf(acc[c], dw[c], d); }
    float* hp = h2a + (size_t)n * 8;
    #pragma unroll
    for (int c = 0; c < 7; ++c) hp[c] = acc[c];
    hp[7] = s;                                  // as2 packed into the record
    ad2[n] = d;
}

// ---------------- layer-2 edge pass + bias + log_softmax: 8 lanes/node, 16-edge batches ----------------
__global__ __launch_bounds__(256) void k_layer2(const float* __restrict__ ad2,
    const float* __restrict__ h2a, const int* __restrict__ row_off, const int* __restrict__ csr,
    const float* __restrict__ b2, float* __restrict__ out)
{
    int tid  = threadIdx.x;
    int node = blockIdx.x * 32 + (tid >> 3);
    int c    = tid & 7;
    int lane = tid & 63;
    int gb   = lane & ~7;                        // 8-lane group base within wave
    if (node >= NN) return;
    float adv   = ad2[node];
    float vself = h2a[(size_t)node * 8 + c];
    float as_n  = __shfl(vself, gb + 7, 64);
    float e0 = leaky02(as_n + adv);
    float p0 = __expf(e0 - 20.f);
    float den = p0;
    float acc = p0 * vself;                      // c==7 lane accumulates garbage; unused
    int beg = row_off[node], end = row_off[node + 1];
    for (int base = beg; base < end; base += 16){
        int cnt = end - base; if (cnt > 16) cnt = 16;
        int j1  = 8 + c;
        int cs0 = csr[base + (c  < cnt ? c  : cnt - 1)];
        int cs1 = csr[base + (j1 < cnt ? j1 : cnt - 1)];
        float val[16];
        #pragma unroll
        for (int t = 0; t < 16; ++t){
            if (t < cnt){
                int s = (t < 8) ? __shfl(cs0, gb + t, 64) : __shfl(cs1, gb + t - 8, 64);
                val[t] = h2a[(size_t)s * 8 + c];
            }
        }
        #pragma unroll
        for (int t = 0; t < 16; ++t){
            if (t < cnt){
                float as_s = __shfl(val[t], gb + 7, 64);
                float e = leaky02(as_s + adv);
                float p = __expf(e - 20.f);
                den += p;
                acc  = fmaf(p, val[t], acc);
            }
        }
    }
    float v = (c < 7) ? (acc / den + b2[c]) : -1e30f;
    float m = v;
    m = fmaxf(m, __shfl_xor(m, 1, 64));
    m = fmaxf(m, __shfl_xor(m, 2, 64));
    m = fmaxf(m, __shfl_xor(m, 4, 64));
    float ex = (c < 7) ? __expf(v - m) : 0.f;
    float s7 = ex;
    s7 += __shfl_xor(s7, 1, 64);
    s7 += __shfl_xor(s7, 2, 64);
    s7 += __shfl_xor(s7, 4, 64);
    if (c < 7) out[(size_t)node * 7 + c] = v - m - __logf(s7);
}

// ---------------- launcher ----------------
extern "C" void kernel_launch(void* const* d_in, const int* in_sizes, int n_in,
                              void* d_out, int out_size, void* d_ws, size_t ws_size,
                              hipStream_t stream)
{
    (void)n_in; (void)out_size; (void)ws_size;
    const float* x      = (const float*)d_in[0];
    const int*   ei     = (const int*)d_in[1];
    const int    E      = in_sizes[1] / 2;
    const float* W1     = (const float*)d_in[2];
    const float* asrc1  = (const float*)d_in[3];
    const float* adst1  = (const float*)d_in[4];
    const float* b1     = (const float*)d_in[5];
    const float* W2     = (const float*)d_in[6];
    const float* asrc2  = (const float*)d_in[7];
    const float* adst2  = (const float*)d_in[8];
    const float* b2     = (const float*)d_in[9];
    float* out = (float*)d_out;

    char* p = (char*)d_ws;
    auto alloc = [&](size_t bytes) -> void* {
        void* r = (void*)p;
        p += (bytes + 255) & ~(size_t)255;
        return r;
    };
    int*    deg     = (int*)alloc((size_t)NN * 4);
    int*    row_off = (int*)alloc((size_t)(NN + 1) * 4);
    int*    rank    = (int*)alloc((size_t)E * 4);
    int*    bsum    = (int*)alloc((size_t)NB_SCAN * 4);
    int*    csr     = (int*)alloc((size_t)E * 4);
    __bf16* w1h     = (__bf16*)alloc((size_t)64 * KPAD * 2);
    __bf16* w1l     = (__bf16*)alloc((size_t)64 * KPAD * 2);
    __bf16* Hb0     = (__bf16*)alloc((size_t)NN * 32 * 2);
    __bf16* Hb1     = (__bf16*)alloc((size_t)NN * 32 * 2);
    __bf16* asadA   = (__bf16*)alloc((size_t)NN * 8 * 2);
    __bf16* asadB   = (__bf16*)alloc((size_t)NN * 8 * 2);
    float*  x2      = (float*)alloc((size_t)NN * 64 * 4);
    float*  h2a     = (float*)alloc((size_t)NN * 8 * 4);
    float*  ad2     = (float*)alloc((size_t)NN * 4);

    const int* src = ei;
    const int* dst = ei + E;

    k_prep   <<<64 + NB_SCAN, 256, 0, stream>>>(W1, w1h, w1l, deg);
    k_rank   <<<(E + 1023) / 1024, 256, 0, stream>>>(dst, deg, rank, E);
    k_scan1  <<<NB_SCAN, 256, 0, stream>>>(deg, bsum);
    k_scan3  <<<NB_SCAN, 256, 0, stream>>>(deg, bsum, row_off);
    k_scatter<<<(E + 1023) / 1024, 256, 0, stream>>>(src, dst, rank, row_off, csr, E);
    k_gemm1  <<<(NN + 63) / 64, 256, 0, stream>>>(x, w1h, w1l, asrc1, adst1,
                                                  Hb0, Hb1, asadA, asadB);
    k_layer1 <<<2 * L1B, 256, 0, stream>>>(asadA, asadB, Hb0, Hb1, row_off, csr, b1, x2);
    k_gemm2  <<<(NN + 255) / 256, 256, 0, stream>>>(x2, W2, asrc2, adst2, h2a, ad2);
    k_layer2 <<<(NN + 31) / 32, 256, 0, stream>>>(ad2, h2a, row_off, csr, b2, out);
}

// Round 13
// 298.330 us; speedup vs baseline: 2.5150x; 1.1012x over previous
//
#include <hip/hip_runtime.h>
#include <hip/hip_bf16.h>

static constexpr int NN      = 50000;
static constexpr int FIN     = 1433;
static constexpr int KPAD    = 1440;            // 45 * 32
static constexpr int NB_SCAN = (NN + 255) / 256; // 196
static constexpr int L1B     = NN / 4;           // 12500 blocks, 1 node/wave

typedef __bf16 bf16x8 __attribute__((ext_vector_type(8)));
typedef float  f32x4  __attribute__((ext_vector_type(4)));

__device__ __forceinline__ float leaky02(float v){ return v >= 0.f ? v : 0.2f * v; }
__device__ __forceinline__ float bflo(unsigned u){ return __uint_as_float(u << 16); }
__device__ __forceinline__ float bfhi(unsigned u){ return __uint_as_float(u & 0xffff0000u); }

// async global->LDS, 4 bytes/lane: lane l writes lds_base + l*4
__device__ __forceinline__ void gld_lds4(const float* g, float* l){
    __builtin_amdgcn_global_load_lds(
        (const __attribute__((address_space(1))) unsigned int*)g,
        (__attribute__((address_space(3))) unsigned int*)l, 4, 0, 0);
}

// ---------------- prep: W1 transpose/split + deg zero, one dispatch ----------------
__global__ __launch_bounds__(256) void k_prep(const float* __restrict__ W1,
                                              __bf16* __restrict__ w1h, __bf16* __restrict__ w1l,
                                              int* __restrict__ deg){
    int bid = blockIdx.x;
    if (bid < 64){
        int c = bid;                          // output column
        for (int k = threadIdx.x; k < KPAD; k += 256){
            float v = (k < FIN) ? W1[(size_t)k * 64 + c] : 0.f;
            __bf16 hi = (__bf16)v;
            w1h[(size_t)c * KPAD + k] = hi;
            w1l[(size_t)c * KPAD + k] = (__bf16)(v - (float)hi);
        }
    } else {
        int i = (bid - 64) * 256 + threadIdx.x;
        if (i < NN) deg[i] = 0;
    }
}

// ---------------- CSR build ----------------
__global__ __launch_bounds__(256) void k_rank(const int* __restrict__ dst, int* __restrict__ deg,
                                              int* __restrict__ rank, int E){
    int base = blockIdx.x * 1024 + threadIdx.x;
    int d[4]; bool v[4];
    #pragma unroll
    for (int i = 0; i < 4; ++i){
        int e = base + i * 256;
        v[i] = e < E;
        d[i] = v[i] ? dst[e] : 0;
    }
    int r[4];
    #pragma unroll
    for (int i = 0; i < 4; ++i)
        if (v[i]) r[i] = atomicAdd(&deg[d[i]], 1);
    #pragma unroll
    for (int i = 0; i < 4; ++i)
        if (v[i]) rank[base + i * 256] = r[i];
}

__global__ __launch_bounds__(256) void k_scan1(const int* __restrict__ deg, int* __restrict__ bsum){
    __shared__ int red[256];
    int i = blockIdx.x * 256 + threadIdx.x;
    red[threadIdx.x] = (i < NN) ? deg[i] : 0;
    __syncthreads();
    for (int off = 128; off > 0; off >>= 1){
        if (threadIdx.x < off) red[threadIdx.x] += red[threadIdx.x + off];
        __syncthreads();
    }
    if (threadIdx.x == 0) bsum[blockIdx.x] = red[0];
}

// scan3 with scan2 folded in
__global__ __launch_bounds__(256) void k_scan3(const int* __restrict__ deg, const int* __restrict__ bsum,
                                               int* __restrict__ row_off){
    __shared__ int s[256];
    int t = threadIdx.x;
    int i = blockIdx.x * 256 + t;
    s[t] = (t < blockIdx.x) ? bsum[t] : 0;
    __syncthreads();
    for (int off = 128; off > 0; off >>= 1){
        if (t < off) s[t] += s[t + off];
        __syncthreads();
    }
    int bofs = s[0];
    __syncthreads();
    int d = (i < NN) ? deg[i] : 0;
    s[t] = d;
    __syncthreads();
    for (int off = 1; off < 256; off <<= 1){
        int v = s[t];
        int a = (t >= off) ? s[t - off] : 0;
        __syncthreads();
        s[t] = v + a;
        __syncthreads();
    }
    int excl = s[t] - d + bofs;
    if (i < NN){
        row_off[i] = excl;
        if (i == NN - 1) row_off[NN] = excl + d;
    }
}

__global__ __launch_bounds__(256) void k_scatter(const int* __restrict__ src, const int* __restrict__ dst,
                                                 const int* __restrict__ rank, const int* __restrict__ row_off,
                                                 int* __restrict__ csr, int E){
    int base = blockIdx.x * 1024 + threadIdx.x;
    int d[4], r[4], sv[4]; bool v[4];
    #pragma unroll
    for (int i = 0; i < 4; ++i){
        int e = base + i * 256;
        v[i] = e < E;
        if (v[i]){ d[i] = dst[e]; r[i] = rank[e]; sv[i] = src[e]; }
    }
    int ro[4];
    #pragma unroll
    for (int i = 0; i < 4; ++i)
        if (v[i]) ro[i] = row_off[d[i]];
    #pragma unroll
    for (int i = 0; i < 4; ++i)
        if (v[i]) csr[ro[i] + r[i]] = sv[i];
}

// ---------------- GEMM1: H = x @ W1 (+ fused alpha1) ----------------
// Outputs: Hb [N][64] bf16 (128B line-aligned rows), asad [N][16] bf16
// ([0..7]=as per head, [8..15]=ad per head).
__global__ __launch_bounds__(256, 4) void k_gemm1(const float* __restrict__ x,
    const __bf16* __restrict__ w1h, const __bf16* __restrict__ w1l,
    const float* __restrict__ a_s, const float* __restrict__ a_d,
    __bf16* __restrict__ Hb, __bf16* __restrict__ asad)
{
    __shared__ float  As[64 * 68];           // 17.4 KB f32 staging (stride 68)
    __shared__ __bf16 AH[64 * 72];           // 9.2 KB hi plane (stride 72)
    __shared__ __bf16 AL[64 * 72];           // 9.2 KB lo plane
    const int tid  = threadIdx.x;
    const int w    = tid >> 6;
    const int lane = tid & 63;
    const int lr   = lane & 15;
    const int lk   = lane >> 4;
    const int rbase = blockIdx.x * 64;
    const int cr = tid >> 2;
    const int cg = (tid & 3) * 16;

    unsigned rowoff[16];
    #pragma unroll
    for (int i = 0; i < 16; ++i){
        int rg = rbase + w * 16 + i; if (rg >= NN) rg = NN - 1;
        rowoff[i] = (unsigned)rg * (unsigned)FIN + (unsigned)lane;
    }

    const __bf16* bh_p = w1h + (size_t)(w * 16 + lr) * KPAD + lk * 8;
    const __bf16* bl_p = w1l + (size_t)(w * 16 + lr) * KPAD + lk * 8;

    f32x4 acc[4] = {{0,0,0,0},{0,0,0,0},{0,0,0,0},{0,0,0,0}};

    #pragma unroll
    for (int i = 0; i < 16; ++i)
        gld_lds4(x + rowoff[i], &As[(w * 16 + i) * 68]);
    __syncthreads();

    for (int kb = 0; kb < 22; ++kb){
        {   // one-time convert As -> AH/AL
            const float* rp = &As[cr * 68 + cg];
            f32x4 v[4];
            #pragma unroll
            for (int j = 0; j < 4; ++j) v[j] = *(const f32x4*)(rp + j * 4);
            bf16x8 hv0, hv1, lv0, lv1;
            #pragma unroll
            for (int j = 0; j < 2; ++j){
                #pragma unroll
                for (int e = 0; e < 4; ++e){
                    float a0 = v[2 * j][e], a1 = v[2 * j + 1][e];
                    __bf16 h0 = (__bf16)a0, h1 = (__bf16)a1;
                    if (j == 0){ hv0[e] = h0; hv0[e + 4] = h1;
                                 lv0[e] = (__bf16)(a0 - (float)h0);
                                 lv0[e + 4] = (__bf16)(a1 - (float)h1); }
                    else       { hv1[e] = h0; hv1[e + 4] = h1;
                                 lv1[e] = (__bf16)(a0 - (float)h0);
                                 lv1[e + 4] = (__bf16)(a1 - (float)h1); }
                }
            }
            *(bf16x8*)&AH[cr * 72 + cg]     = hv0;
            *(bf16x8*)&AH[cr * 72 + cg + 8] = hv1;
            *(bf16x8*)&AL[cr * 72 + cg]     = lv0;
            *(bf16x8*)&AL[cr * 72 + cg + 8] = lv1;
        }
        __syncthreads();

        if (kb < 21){
            const float* gsrc = x + (kb + 1) * 64;
            #pragma unroll
            for (int i = 0; i < 16; ++i)
                gld_lds4(gsrc + rowoff[i], &As[(w * 16 + i) * 68]);
        }

        const int kA = kb * 64;
        bf16x8 bh0 = *(const bf16x8*)(bh_p + kA);
        bf16x8 bl0 = *(const bf16x8*)(bl_p + kA);
        bf16x8 bh1 = *(const bf16x8*)(bh_p + kA + 32);
        bf16x8 bl1 = *(const bf16x8*)(bl_p + kA + 32);
        #pragma unroll
        for (int ks = 0; ks < 2; ++ks){
            bf16x8 bh = ks ? bh1 : bh0;
            bf16x8 bl = ks ? bl1 : bl0;
            #pragma unroll
            for (int t = 0; t < 4; ++t){
                const int ao = (t * 16 + lr) * 72 + ks * 32 + lk * 8;
                bf16x8 ah = *(const bf16x8*)&AH[ao];
                bf16x8 al = *(const bf16x8*)&AL[ao];
                acc[t] = __builtin_amdgcn_mfma_f32_16x16x32_bf16(ah, bh, acc[t], 0, 0, 0);
                acc[t] = __builtin_amdgcn_mfma_f32_16x16x32_bf16(al, bh, acc[t], 0, 0, 0);
                acc[t] = __builtin_amdgcn_mfma_f32_16x16x32_bf16(ah, bl, acc[t], 0, 0, 0);
            }
        }
        __syncthreads();
    }

    // peeled masked tail: k 1408..1439 (valid < 1433)
    {
        bf16x8 bh = *(const bf16x8*)(bh_p + 1408);
        bf16x8 bl = *(const bf16x8*)(bl_p + 1408);
        #pragma unroll
        for (int t = 0; t < 4; ++t){
            int rg = rbase + t * 16 + lr; if (rg >= NN) rg = NN - 1;
            const float* xr = x + (size_t)rg * FIN;
            bf16x8 ah, al;
            #pragma unroll
            for (int e = 0; e < 8; ++e){
                int k = 1408 + lk * 8 + e;
                float v = (k < FIN) ? xr[k] : 0.f;
                __bf16 h = (__bf16)v;
                ah[e] = h; al[e] = (__bf16)(v - (float)h);
            }
            acc[t] = __builtin_amdgcn_mfma_f32_16x16x32_bf16(ah, bh, acc[t], 0, 0, 0);
            acc[t] = __builtin_amdgcn_mfma_f32_16x16x32_bf16(al, bh, acc[t], 0, 0, 0);
            acc[t] = __builtin_amdgcn_mfma_f32_16x16x32_bf16(ah, bl, acc[t], 0, 0, 0);
        }
    }

    // epilogue 1: H tile -> LDS (As, f32) + bf16 stores to Hb[N][64]
    __syncthreads();
    const int col = w * 16 + lr;
    #pragma unroll
    for (int t = 0; t < 4; ++t){
        #pragma unroll
        for (int r = 0; r < 4; ++r){
            int rib = t * 16 + lk * 4 + r;
            float v = acc[t][r];
            As[rib * 68 + col] = v;
            int row = rbase + rib;
            if (row < NN) Hb[(size_t)row * 64 + col] = (__bf16)v;
        }
    }
    __syncthreads();
    // epilogue 2: fused alpha1 -> asad[N][16] ([0..7]=as, [8..15]=ad)
    #pragma unroll
    for (int it = 0; it < 2; ++it){
        int task = tid + it * 256;
        int row  = task >> 3;
        int hh   = task & 7;
        int grow = rbase + row;
        if (grow < NN){
            const float* hr = &As[row * 68 + hh * 8];
            float s = 0.f, dd = 0.f;
            #pragma unroll
            for (int c = 0; c < 8; ++c){
                float v = hr[c];
                s  = fmaf(v, a_s[hh * 8 + c], s);
                dd = fmaf(v, a_d[hh * 8 + c], dd);
            }
            asad[(size_t)grow * 16 + hh]     = (__bf16)s;
            asad[(size_t)grow * 16 + 8 + hh] = (__bf16)dd;
        }
    }
}

// ---------------- layer-1 edge pass, ONE pass over edges, all 64 channels ----------------
// wave = 1 dst node; lane l = (edge slot e8 = l>>3) x (head c8 = l&7 -> 8 channels, uint4).
// Per 8-edge batch: 1 csr + 1 uint4 H (8 full 128B rows) + 1 as load = 3 wave-VMEM
// for ALL channels (0.38 VMEM/edge total vs 0.75 in the 2-pass version).
__global__ __launch_bounds__(256, 8) void k_layer1(const __bf16* __restrict__ asad,
    const __bf16* __restrict__ Hb, const int* __restrict__ row_off, const int* __restrict__ csr,
    const float* __restrict__ b1, float* __restrict__ x2)
{
    const int d  = blockIdx.x * 4 + (threadIdx.x >> 6);
    const int l  = threadIdx.x & 63;
    const int e8 = l >> 3;           // edge slot (0..7)
    const int c8 = l & 7;            // head = channel chunk of 8 (uint4)
    const int c0 = c8 * 8;
    const float adv = (float)asad[(size_t)d * 16 + 8 + c8];

    float den = 0.f;
    float a[8] = {0.f,0.f,0.f,0.f,0.f,0.f,0.f,0.f};
    if (e8 == 0){
        float as_d = (float)asad[(size_t)d * 16 + c8];
        float p0 = __expf(leaky02(as_d + adv) - 20.f);   // fixed-offset softmax (e << 20)
        uint4 hw = *(const uint4*)&Hb[(size_t)d * 64 + c0];
        den = p0;
        a[0] = p0 * bflo(hw.x); a[1] = p0 * bfhi(hw.x);
        a[2] = p0 * bflo(hw.y); a[3] = p0 * bfhi(hw.y);
        a[4] = p0 * bflo(hw.z); a[5] = p0 * bfhi(hw.z);
        a[6] = p0 * bflo(hw.w); a[7] = p0 * bfhi(hw.w);
    }

    const int beg = row_off[d], end = row_off[d + 1];
    const int nb = (end - beg + 7) >> 3;     // 8-edge batches
    int csrv = 0;
    if (nb > 0){
        int idx = beg + c8; if (idx >= end) idx = end - 1;
        csrv = __builtin_nontemporal_load(csr + idx);
    }
    for (int b = 0; b < nb; ++b){
        const int base = beg + b * 8;
        int ncsr = 0;
        if (b + 1 < nb){
            int idx = base + 8 + c8; if (idx >= end) idx = end - 1;
            ncsr = __builtin_nontemporal_load(csr + idx);
        }
        int s = __shfl(csrv, e8, 8);         // edge (base+e8)'s src for this lane's group
        const bool val = (base + e8) < end;
        uint4 hw = make_uint4(0u,0u,0u,0u); float av = 0.f;
        if (val){
            hw = *(const uint4*)&Hb[(size_t)s * 64 + c0];
            av = (float)asad[(size_t)s * 16 + c8];
        }
        if (val){
            float p = __expf(leaky02(av + adv) - 20.f);
            den += p;
            a[0] = fmaf(p, bflo(hw.x), a[0]); a[1] = fmaf(p, bfhi(hw.x), a[1]);
            a[2] = fmaf(p, bflo(hw.y), a[2]); a[3] = fmaf(p, bfhi(hw.y), a[3]);
            a[4] = fmaf(p, bflo(hw.z), a[4]); a[5] = fmaf(p, bfhi(hw.z), a[5]);
            a[6] = fmaf(p, bflo(hw.w), a[6]); a[7] = fmaf(p, bfhi(hw.w), a[7]);
        }
        csrv = ncsr;
    }

    // reduce over edge slots (lane bits 3..5)
    #pragma unroll
    for (int m = 8; m <= 32; m <<= 1){
        den += __shfl_xor(den, m, 64);
        #pragma unroll
        for (int j = 0; j < 8; ++j) a[j] += __shfl_xor(a[j], m, 64);
    }

    if (e8 == 0){
        float inv = 1.f / den;
        float o[8];
        #pragma unroll
        for (int j = 0; j < 8; ++j){
            float v = a[j] * inv + b1[c0 + j];
            o[j] = (v > 0.f) ? v : (__expf(v) - 1.f);    // ELU fused
        }
        float4 o0 = make_float4(o[0], o[1], o[2], o[3]);
        float4 o1 = make_float4(o[4], o[5], o[6], o[7]);
        float* xp = &x2[(size_t)d * 64 + c0];
        *(float4*)xp       = o0;
        *(float4*)(xp + 4) = o1;
    }
}

// ---------------- GEMM2 + attention logits, layer 2 ----------------
__global__ __launch_bounds__(256) void k_gemm2(const float* __restrict__ x2, const float* __restrict__ W2,
    const float* __restrict__ aw_in, const float* __restrict__ dw_in,
    float* __restrict__ h2a, float* __restrict__ ad2)
{
    __shared__ float w2s[448];
    __shared__ float aw[7], dw[7];
    int tid = threadIdx.x;
    for (int i = tid; i < 448; i += 256) w2s[i] = W2[i];
    if (tid < 7){ aw[tid] = aw_in[tid]; dw[tid] = dw_in[tid]; }
    __syncthreads();
    int n = blockIdx.x * 256 + tid;
    if (n >= NN) return;
    const float4* xp = (const float4*)(x2 + (size_t)n * 64);
    float acc[7] = {0.f,0.f,0.f,0.f,0.f,0.f,0.f};
    #pragma unroll
    for (int q = 0; q < 16; ++q){
        float4 v = xp[q];
        float vv[4] = {v.x, v.y, v.z, v.w};
        #pragma unroll
        for (int u = 0; u < 4; ++u){
            int k = q * 4 + u;
            #pragma unroll
            for (int c = 0; c < 7; ++c) acc[c] = fmaf(vv[u], w2s[k * 7 + c], acc[c]);
        }
    }
    float s = 0.f, d = 0.f;
    #pragma unroll
    for (int c = 0; c < 7; ++c){ s = fmaf(acc[c], aw[c], s); d = fmaf(acc[c], dw[c], d); }
    float* hp = h2a + (size_t)n * 8;
    #pragma unroll
    for (int c = 0; c < 7; ++c) hp[c] = acc[c];
    hp[7] = s;                                  // as2 packed into the record
    ad2[n] = d;
}

// ---------------- layer-2 edge pass + bias + log_softmax: 8 lanes/node, 16-edge batches ----------------
__global__ __launch_bounds__(256) void k_layer2(const float* __restrict__ ad2,
    const float* __restrict__ h2a, const int* __restrict__ row_off, const int* __restrict__ csr,
    const float* __restrict__ b2, float* __restrict__ out)
{
    int tid  = threadIdx.x;
    int node = blockIdx.x * 32 + (tid >> 3);
    int c    = tid & 7;
    int lane = tid & 63;
    int gb   = lane & ~7;                        // 8-lane group base within wave
    if (node >= NN) return;
    float adv   = ad2[node];
    float vself = h2a[(size_t)node * 8 + c];
    float as_n  = __shfl(vself, gb + 7, 64);
    float e0 = leaky02(as_n + adv);
    float p0 = __expf(e0 - 20.f);
    float den = p0;
    float acc = p0 * vself;                      // c==7 lane accumulates garbage; unused
    int beg = row_off[node], end = row_off[node + 1];
    for (int base = beg; base < end; base += 16){
        int cnt = end - base; if (cnt > 16) cnt = 16;
        int j1  = 8 + c;
        int cs0 = csr[base + (c  < cnt ? c  : cnt - 1)];
        int cs1 = csr[base + (j1 < cnt ? j1 : cnt - 1)];
        float val[16];
        #pragma unroll
        for (int t = 0; t < 16; ++t){
            if (t < cnt){
                int s = (t < 8) ? __shfl(cs0, gb + t, 64) : __shfl(cs1, gb + t - 8, 64);
                val[t] = h2a[(size_t)s * 8 + c];
            }
        }
        #pragma unroll
        for (int t = 0; t < 16; ++t){
            if (t < cnt){
                float as_s = __shfl(val[t], gb + 7, 64);
                float e = leaky02(as_s + adv);
                float p = __expf(e - 20.f);
                den += p;
                acc  = fmaf(p, val[t], acc);
            }
        }
    }
    float v = (c < 7) ? (acc / den + b2[c]) : -1e30f;
    float m = v;
    m = fmaxf(m, __shfl_xor(m, 1, 64));
    m = fmaxf(m, __shfl_xor(m, 2, 64));
    m = fmaxf(m, __shfl_xor(m, 4, 64));
    float ex = (c < 7) ? __expf(v - m) : 0.f;
    float s7 = ex;
    s7 += __shfl_xor(s7, 1, 64);
    s7 += __shfl_xor(s7, 2, 64);
    s7 += __shfl_xor(s7, 4, 64);
    if (c < 7) out[(size_t)node * 7 + c] = v - m - __logf(s7);
}

// ---------------- launcher ----------------
extern "C" void kernel_launch(void* const* d_in, const int* in_sizes, int n_in,
                              void* d_out, int out_size, void* d_ws, size_t ws_size,
                              hipStream_t stream)
{
    (void)n_in; (void)out_size; (void)ws_size;
    const float* x      = (const float*)d_in[0];
    const int*   ei     = (const int*)d_in[1];
    const int    E      = in_sizes[1] / 2;
    const float* W1     = (const float*)d_in[2];
    const float* asrc1  = (const float*)d_in[3];
    const float* adst1  = (const float*)d_in[4];
    const float* b1     = (const float*)d_in[5];
    const float* W2     = (const float*)d_in[6];
    const float* asrc2  = (const float*)d_in[7];
    const float* adst2  = (const float*)d_in[8];
    const float* b2     = (const float*)d_in[9];
    float* out = (float*)d_out;

    char* p = (char*)d_ws;
    auto alloc = [&](size_t bytes) -> void* {
        void* r = (void*)p;
        p += (bytes + 255) & ~(size_t)255;
        return r;
    };
    int*    deg     = (int*)alloc((size_t)NN * 4);
    int*    row_off = (int*)alloc((size_t)(NN + 1) * 4);
    int*    rank    = (int*)alloc((size_t)E * 4);
    int*    bsum    = (int*)alloc((size_t)NB_SCAN * 4);
    int*    csr     = (int*)alloc((size_t)E * 4);
    __bf16* w1h     = (__bf16*)alloc((size_t)64 * KPAD * 2);
    __bf16* w1l     = (__bf16*)alloc((size_t)64 * KPAD * 2);
    __bf16* Hb      = (__bf16*)alloc((size_t)NN * 64 * 2);   // 128B rows
    __bf16* asad    = (__bf16*)alloc((size_t)NN * 16 * 2);
    float*  x2      = (float*)alloc((size_t)NN * 64 * 4);
    float*  h2a     = (float*)alloc((size_t)NN * 8 * 4);
    float*  ad2     = (float*)alloc((size_t)NN * 4);

    const int* src = ei;
    const int* dst = ei + E;

    k_prep   <<<64 + NB_SCAN, 256, 0, stream>>>(W1, w1h, w1l, deg);
    k_rank   <<<(E + 1023) / 1024, 256, 0, stream>>>(dst, deg, rank, E);
    k_scan1  <<<NB_SCAN, 256, 0, stream>>>(deg, bsum);
    k_scan3  <<<NB_SCAN, 256, 0, stream>>>(deg, bsum, row_off);
    k_scatter<<<(E + 1023) / 1024, 256, 0, stream>>>(src, dst, rank, row_off, csr, E);
    k_gemm1  <<<(NN + 63) / 64, 256, 0, stream>>>(x, w1h, w1l, asrc1, adst1, Hb, asad);
    k_layer1 <<<L1B, 256, 0, stream>>>(asad, Hb, row_off, csr, b1, x2);
    k_gemm2  <<<(NN + 255) / 256, 256, 0, stream>>>(x2, W2, asrc2, adst2, h2a, ad2);
    k_layer2 <<<(NN + 31) / 32, 256, 0, stream>>>(ad2, h2a, row_off, csr, b2, out);
}

// Round 14
// 289.841 us; speedup vs baseline: 2.5887x; 1.0293x over previous
//
#include <hip/hip_runtime.h>
#include <hip/hip_bf16.h>

static constexpr int NN      = 50000;
static constexpr int FIN     = 1433;
static constexpr int KPAD    = 1440;            // 45 * 32
static constexpr int NB_SCAN = (NN + 255) / 256; // 196
static constexpr int L1B     = NN / 4;           // 12500 blocks, 1 node/wave

typedef __bf16 bf16x8 __attribute__((ext_vector_type(8)));
typedef float  f32x4  __attribute__((ext_vector_type(4)));

__device__ __forceinline__ float leaky02(float v){ return v >= 0.f ? v : 0.2f * v; }
__device__ __forceinline__ float bflo(unsigned u){ return __uint_as_float(u << 16); }
__device__ __forceinline__ float bfhi(unsigned u){ return __uint_as_float(u & 0xffff0000u); }

// async global->LDS, 4 bytes/lane: lane l writes lds_base + l*4
__device__ __forceinline__ void gld_lds4(const float* g, float* l){
    __builtin_amdgcn_global_load_lds(
        (const __attribute__((address_space(1))) unsigned int*)g,
        (__attribute__((address_space(3))) unsigned int*)l, 4, 0, 0);
}

// ---------------- prep: W1 transpose/split + deg zero, one dispatch ----------------
__global__ __launch_bounds__(256) void k_prep(const float* __restrict__ W1,
                                              __bf16* __restrict__ w1h, __bf16* __restrict__ w1l,
                                              int* __restrict__ deg){
    int bid = blockIdx.x;
    if (bid < 64){
        int c = bid;                          // output column
        for (int k = threadIdx.x; k < KPAD; k += 256){
            float v = (k < FIN) ? W1[(size_t)k * 64 + c] : 0.f;
            __bf16 hi = (__bf16)v;
            w1h[(size_t)c * KPAD + k] = hi;
            w1l[(size_t)c * KPAD + k] = (__bf16)(v - (float)hi);
        }
    } else {
        int i = (bid - 64) * 256 + threadIdx.x;
        if (i < NN) deg[i] = 0;
    }
}

// ---------------- CSR build ----------------
__global__ __launch_bounds__(256) void k_rank(const int* __restrict__ dst, int* __restrict__ deg,
                                              int* __restrict__ rank, int E){
    int base = blockIdx.x * 1024 + threadIdx.x;
    int d[4]; bool v[4];
    #pragma unroll
    for (int i = 0; i < 4; ++i){
        int e = base + i * 256;
        v[i] = e < E;
        d[i] = v[i] ? dst[e] : 0;
    }
    int r[4];
    #pragma unroll
    for (int i = 0; i < 4; ++i)
        if (v[i]) r[i] = atomicAdd(&deg[d[i]], 1);
    #pragma unroll
    for (int i = 0; i < 4; ++i)
        if (v[i]) rank[base + i * 256] = r[i];
}

__global__ __launch_bounds__(256) void k_scan1(const int* __restrict__ deg, int* __restrict__ bsum){
    __shared__ int red[256];
    int i = blockIdx.x * 256 + threadIdx.x;
    red[threadIdx.x] = (i < NN) ? deg[i] : 0;
    __syncthreads();
    for (int off = 128; off > 0; off >>= 1){
        if (threadIdx.x < off) red[threadIdx.x] += red[threadIdx.x + off];
        __syncthreads();
    }
    if (threadIdx.x == 0) bsum[blockIdx.x] = red[0];
}

// scan3 with scan2 folded in
__global__ __launch_bounds__(256) void k_scan3(const int* __restrict__ deg, const int* __restrict__ bsum,
                                               int* __restrict__ row_off){
    __shared__ int s[256];
    int t = threadIdx.x;
    int i = blockIdx.x * 256 + t;
    s[t] = (t < blockIdx.x) ? bsum[t] : 0;
    __syncthreads();
    for (int off = 128; off > 0; off >>= 1){
        if (t < off) s[t] += s[t + off];
        __syncthreads();
    }
    int bofs = s[0];
    __syncthreads();
    int d = (i < NN) ? deg[i] : 0;
    s[t] = d;
    __syncthreads();
    for (int off = 1; off < 256; off <<= 1){
        int v = s[t];
        int a = (t >= off) ? s[t - off] : 0;
        __syncthreads();
        s[t] = v + a;
        __syncthreads();
    }
    int excl = s[t] - d + bofs;
    if (i < NN){
        row_off[i] = excl;
        if (i == NN - 1) row_off[NN] = excl + d;
    }
}

__global__ __launch_bounds__(256) void k_scatter(const int* __restrict__ src, const int* __restrict__ dst,
                                                 const int* __restrict__ rank, const int* __restrict__ row_off,
                                                 int* __restrict__ csr, int E){
    int base = blockIdx.x * 1024 + threadIdx.x;
    int d[4], r[4], sv[4]; bool v[4];
    #pragma unroll
    for (int i = 0; i < 4; ++i){
        int e = base + i * 256;
        v[i] = e < E;
        if (v[i]){ d[i] = dst[e]; r[i] = rank[e]; sv[i] = src[e]; }
    }
    int ro[4];
    #pragma unroll
    for (int i = 0; i < 4; ++i)
        if (v[i]) ro[i] = row_off[d[i]];
    #pragma unroll
    for (int i = 0; i < 4; ++i)
        if (v[i]) csr[ro[i] + r[i]] = sv[i];
}

// ---------------- GEMM1: H = x @ W1 -> Hb[N][64] bf16 (128B rows) ----------------
__global__ __launch_bounds__(256, 4) void k_gemm1(const float* __restrict__ x,
    const __bf16* __restrict__ w1h, const __bf16* __restrict__ w1l,
    __bf16* __restrict__ Hb)
{
    __shared__ float  As[64 * 68];           // 17.4 KB f32 staging (stride 68)
    __shared__ __bf16 AH[64 * 72];           // 9.2 KB hi plane (stride 72)
    __shared__ __bf16 AL[64 * 72];           // 9.2 KB lo plane
    const int tid  = threadIdx.x;
    const int w    = tid >> 6;
    const int lane = tid & 63;
    const int lr   = lane & 15;
    const int lk   = lane >> 4;
    const int rbase = blockIdx.x * 64;
    const int cr = tid >> 2;
    const int cg = (tid & 3) * 16;

    unsigned rowoff[16];
    #pragma unroll
    for (int i = 0; i < 16; ++i){
        int rg = rbase + w * 16 + i; if (rg >= NN) rg = NN - 1;
        rowoff[i] = (unsigned)rg * (unsigned)FIN + (unsigned)lane;
    }

    const __bf16* bh_p = w1h + (size_t)(w * 16 + lr) * KPAD + lk * 8;
    const __bf16* bl_p = w1l + (size_t)(w * 16 + lr) * KPAD + lk * 8;

    f32x4 acc[4] = {{0,0,0,0},{0,0,0,0},{0,0,0,0},{0,0,0,0}};

    #pragma unroll
    for (int i = 0; i < 16; ++i)
        gld_lds4(x + rowoff[i], &As[(w * 16 + i) * 68]);
    __syncthreads();

    for (int kb = 0; kb < 22; ++kb){
        {   // one-time convert As -> AH/AL
            const float* rp = &As[cr * 68 + cg];
            f32x4 v[4];
            #pragma unroll
            for (int j = 0; j < 4; ++j) v[j] = *(const f32x4*)(rp + j * 4);
            bf16x8 hv0, hv1, lv0, lv1;
            #pragma unroll
            for (int j = 0; j < 2; ++j){
                #pragma unroll
                for (int e = 0; e < 4; ++e){
                    float a0 = v[2 * j][e], a1 = v[2 * j + 1][e];
                    __bf16 h0 = (__bf16)a0, h1 = (__bf16)a1;
                    if (j == 0){ hv0[e] = h0; hv0[e + 4] = h1;
                                 lv0[e] = (__bf16)(a0 - (float)h0);
                                 lv0[e + 4] = (__bf16)(a1 - (float)h1); }
                    else       { hv1[e] = h0; hv1[e + 4] = h1;
                                 lv1[e] = (__bf16)(a0 - (float)h0);
                                 lv1[e + 4] = (__bf16)(a1 - (float)h1); }
                }
            }
            *(bf16x8*)&AH[cr * 72 + cg]     = hv0;
            *(bf16x8*)&AH[cr * 72 + cg + 8] = hv1;
            *(bf16x8*)&AL[cr * 72 + cg]     = lv0;
            *(bf16x8*)&AL[cr * 72 + cg + 8] = lv1;
        }
        __syncthreads();

        if (kb < 21){
            const float* gsrc = x + (kb + 1) * 64;
            #pragma unroll
            for (int i = 0; i < 16; ++i)
                gld_lds4(gsrc + rowoff[i], &As[(w * 16 + i) * 68]);
        }

        const int kA = kb * 64;
        bf16x8 bh0 = *(const bf16x8*)(bh_p + kA);
        bf16x8 bl0 = *(const bf16x8*)(bl_p + kA);
        bf16x8 bh1 = *(const bf16x8*)(bh_p + kA + 32);
        bf16x8 bl1 = *(const bf16x8*)(bl_p + kA + 32);
        #pragma unroll
        for (int ks = 0; ks < 2; ++ks){
            bf16x8 bh = ks ? bh1 : bh0;
            bf16x8 bl = ks ? bl1 : bl0;
            #pragma unroll
            for (int t = 0; t < 4; ++t){
                const int ao = (t * 16 + lr) * 72 + ks * 32 + lk * 8;
                bf16x8 ah = *(const bf16x8*)&AH[ao];
                bf16x8 al = *(const bf16x8*)&AL[ao];
                acc[t] = __builtin_amdgcn_mfma_f32_16x16x32_bf16(ah, bh, acc[t], 0, 0, 0);
                acc[t] = __builtin_amdgcn_mfma_f32_16x16x32_bf16(al, bh, acc[t], 0, 0, 0);
                acc[t] = __builtin_amdgcn_mfma_f32_16x16x32_bf16(ah, bl, acc[t], 0, 0, 0);
            }
        }
        __syncthreads();
    }

    // peeled masked tail: k 1408..1439 (valid < 1433)
    {
        bf16x8 bh = *(const bf16x8*)(bh_p + 1408);
        bf16x8 bl = *(const bf16x8*)(bl_p + 1408);
        #pragma unroll
        for (int t = 0; t < 4; ++t){
            int rg = rbase + t * 16 + lr; if (rg >= NN) rg = NN - 1;
            const float* xr = x + (size_t)rg * FIN;
            bf16x8 ah, al;
            #pragma unroll
            for (int e = 0; e < 8; ++e){
                int k = 1408 + lk * 8 + e;
                float v = (k < FIN) ? xr[k] : 0.f;
                __bf16 h = (__bf16)v;
                ah[e] = h; al[e] = (__bf16)(v - (float)h);
            }
            acc[t] = __builtin_amdgcn_mfma_f32_16x16x32_bf16(ah, bh, acc[t], 0, 0, 0);
            acc[t] = __builtin_amdgcn_mfma_f32_16x16x32_bf16(al, bh, acc[t], 0, 0, 0);
            acc[t] = __builtin_amdgcn_mfma_f32_16x16x32_bf16(ah, bl, acc[t], 0, 0, 0);
        }
    }

    // epilogue: bf16 stores to Hb[N][64]
    const int col = w * 16 + lr;
    #pragma unroll
    for (int t = 0; t < 4; ++t){
        #pragma unroll
        for (int r = 0; r < 4; ++r){
            int row = rbase + t * 16 + lk * 4 + r;
            if (row < NN) Hb[(size_t)row * 64 + col] = (__bf16)acc[t][r];
        }
    }
}

// ---------------- layer-1 edge pass: alpha computed IN-REGISTER from H ----------------
// wave = 1 dst node; lane l = (edge slot e8 = l>>3) x (head c8 = l&7 -> 8 ch, uint4).
// Head c8's channels live entirely in this lane's chunk, so as_src = dot(Hchunk, a_s)
// is a lane-local 8-fma -> NO per-edge alpha gather. 2 VMEM per 8-edge batch.
__global__ __launch_bounds__(256, 8) void k_layer1(const float* __restrict__ a_s,
    const float* __restrict__ a_d,
    const __bf16* __restrict__ Hb, const int* __restrict__ row_off, const int* __restrict__ csr,
    const float* __restrict__ b1, float* __restrict__ x2)
{
    const int d  = blockIdx.x * 4 + (threadIdx.x >> 6);
    const int l  = threadIdx.x & 63;
    const int e8 = l >> 3;           // edge slot (0..7)
    const int c8 = l & 7;            // head
    const int c0 = c8 * 8;

    float asw[8], adw[8];
    #pragma unroll
    for (int j = 0; j < 8; ++j){ asw[j] = a_s[c0 + j]; adw[j] = a_d[c0 + j]; }

    // self row: adv (dst alpha) + self-loop contribution
    float den = 0.f;
    float a[8] = {0.f,0.f,0.f,0.f,0.f,0.f,0.f,0.f};
    float adv;
    {
        uint4 hs = *(const uint4*)&Hb[(size_t)d * 64 + c0];
        float hv[8] = { bflo(hs.x), bfhi(hs.x), bflo(hs.y), bfhi(hs.y),
                        bflo(hs.z), bfhi(hs.z), bflo(hs.w), bfhi(hs.w) };
        float ad_ = 0.f, as_ = 0.f;
        #pragma unroll
        for (int j = 0; j < 8; ++j){
            ad_ = fmaf(hv[j], adw[j], ad_);
            as_ = fmaf(hv[j], asw[j], as_);
        }
        adv = ad_;
        if (e8 == 0){
            float p0 = __expf(leaky02(as_ + adv) - 20.f);   // fixed-offset softmax
            den = p0;
            #pragma unroll
            for (int j = 0; j < 8; ++j) a[j] = p0 * hv[j];
        }
    }

    const int beg = row_off[d], end = row_off[d + 1];
    const int nb = (end - beg + 7) >> 3;     // 8-edge batches
    int csrv = 0;
    if (nb > 0){
        int idx = beg + c8; if (idx >= end) idx = end - 1;
        csrv = __builtin_nontemporal_load(csr + idx);
    }
    for (int b = 0; b < nb; ++b){
        const int base = beg + b * 8;
        int ncsr = 0;
        if (b + 1 < nb){
            int idx = base + 8 + c8; if (idx >= end) idx = end - 1;
            ncsr = __builtin_nontemporal_load(csr + idx);
        }
        int s = __shfl(csrv, e8, 8);
        const bool val = (base + e8) < end;
        uint4 hw = make_uint4(0u,0u,0u,0u);
        if (val) hw = *(const uint4*)&Hb[(size_t)s * 64 + c0];
        if (val){
            float g[8] = { bflo(hw.x), bfhi(hw.x), bflo(hw.y), bfhi(hw.y),
                           bflo(hw.z), bfhi(hw.z), bflo(hw.w), bfhi(hw.w) };
            float av = 0.f;
            #pragma unroll
            for (int j = 0; j < 8; ++j) av = fmaf(g[j], asw[j], av);
            float p = __expf(leaky02(av + adv) - 20.f);
            den += p;
            #pragma unroll
            for (int j = 0; j < 8; ++j) a[j] = fmaf(p, g[j], a[j]);
        }
        csrv = ncsr;
    }

    // reduce over edge slots (lane bits 3..5)
    #pragma unroll
    for (int m = 8; m <= 32; m <<= 1){
        den += __shfl_xor(den, m, 64);
        #pragma unroll
        for (int j = 0; j < 8; ++j) a[j] += __shfl_xor(a[j], m, 64);
    }

    if (e8 == 0){
        float inv = 1.f / den;
        float o[8];
        #pragma unroll
        for (int j = 0; j < 8; ++j){
            float v = a[j] * inv + b1[c0 + j];
            o[j] = (v > 0.f) ? v : (__expf(v) - 1.f);    // ELU fused
        }
        float* xp = &x2[(size_t)d * 64 + c0];
        *(float4*)xp       = make_float4(o[0], o[1], o[2], o[3]);
        *(float4*)(xp + 4) = make_float4(o[4], o[5], o[6], o[7]);
    }
}

// ---------------- GEMM2 + attention logits, layer 2 ----------------
// h2b[n][8] bf16: [0..6] = h2 channels, [7] = as2 (16B record)
__global__ __launch_bounds__(256) void k_gemm2(const float* __restrict__ x2, const float* __restrict__ W2,
    const float* __restrict__ aw_in, const float* __restrict__ dw_in,
    __bf16* __restrict__ h2b, float* __restrict__ ad2)
{
    __shared__ float w2s[448];
    __shared__ float aw[7], dw[7];
    int tid = threadIdx.x;
    for (int i = tid; i < 448; i += 256) w2s[i] = W2[i];
    if (tid < 7){ aw[tid] = aw_in[tid]; dw[tid] = dw_in[tid]; }
    __syncthreads();
    int n = blockIdx.x * 256 + tid;
    if (n >= NN) return;
    const float4* xp = (const float4*)(x2 + (size_t)n * 64);
    float acc[7] = {0.f,0.f,0.f,0.f,0.f,0.f,0.f};
    #pragma unroll
    for (int q = 0; q < 16; ++q){
        float4 v = xp[q];
        float vv[4] = {v.x, v.y, v.z, v.w};
        #pragma unroll
        for (int u = 0; u < 4; ++u){
            int k = q * 4 + u;
            #pragma unroll
            for (int c = 0; c < 7; ++c) acc[c] = fmaf(vv[u], w2s[k * 7 + c], acc[c]);
        }
    }
    float s = 0.f, d = 0.f;
    #pragma unroll
    for (int c = 0; c < 7; ++c){ s = fmaf(acc[c], aw[c], s); d = fmaf(acc[c], dw[c], d); }
    __bf16 rec[8];
    #pragma unroll
    for (int c = 0; c < 7; ++c) rec[c] = (__bf16)acc[c];
    rec[7] = (__bf16)s;                         // as2 packed in slot 7
    *(uint4*)&h2b[(size_t)n * 8] = *(uint4*)rec;
    ad2[n] = d;
}

// ---------------- layer-2 edge pass + bias + log_softmax ----------------
// 8 lanes/node, lane = edge slot; one uint4 load = full record (h2[0..6] + as2).
// 2 VMEM per 8-edge batch per node group.
__global__ __launch_bounds__(256, 8) void k_layer2(const float* __restrict__ ad2,
    const __bf16* __restrict__ h2b, const int* __restrict__ row_off, const int* __restrict__ csr,
    const float* __restrict__ b2, float* __restrict__ out)
{
    int tid  = threadIdx.x;
    int node = blockIdx.x * 32 + (tid >> 3);
    int sl   = tid & 7;                          // edge slot within node group
    if (node >= NN) return;
    float adv = ad2[node];

    float den = 0.f;
    float a[7] = {0.f,0.f,0.f,0.f,0.f,0.f,0.f};
    {   // self loop (once, slot 0)
        uint4 hs = *(const uint4*)&h2b[(size_t)node * 8];
        float h[8] = { bflo(hs.x), bfhi(hs.x), bflo(hs.y), bfhi(hs.y),
                       bflo(hs.z), bfhi(hs.z), bflo(hs.w), bfhi(hs.w) };
        if (sl == 0){
            float p0 = __expf(leaky02(h[7] + adv) - 20.f);
            den = p0;
            #pragma unroll
            for (int c = 0; c < 7; ++c) a[c] = p0 * h[c];
        }
    }

    const int beg = row_off[node], end = row_off[node + 1];
    const int nb = (end - beg + 7) >> 3;
    int csrv = 0;
    if (nb > 0){
        int idx = beg + sl; if (idx >= end) idx = end - 1;
        csrv = __builtin_nontemporal_load(csr + idx);
    }
    for (int b = 0; b < nb; ++b){
        const int base = beg + b * 8;
        int ncsr = 0;
        if (b + 1 < nb){
            int idx = base + 8 + sl; if (idx >= end) idx = end - 1;
            ncsr = __builtin_nontemporal_load(csr + idx);
        }
        const bool val = (base + sl) < end;
        uint4 hw = make_uint4(0u,0u,0u,0u);
        if (val) hw = *(const uint4*)&h2b[(size_t)csrv * 8];
        if (val){
            float g[8] = { bflo(hw.x), bfhi(hw.x), bflo(hw.y), bfhi(hw.y),
                           bflo(hw.z), bfhi(hw.z), bflo(hw.w), bfhi(hw.w) };
            float p = __expf(leaky02(g[7] + adv) - 20.f);
            den += p;
            #pragma unroll
            for (int c = 0; c < 7; ++c) a[c] = fmaf(p, g[c], a[c]);
        }
        csrv = ncsr;
    }

    // reduce within the node's 8 lanes (lane bits 0..2)
    #pragma unroll
    for (int m = 1; m <= 4; m <<= 1){
        den += __shfl_xor(den, m, 64);
        #pragma unroll
        for (int c = 0; c < 7; ++c) a[c] += __shfl_xor(a[c], m, 64);
    }

    if (sl == 0){
        float inv = 1.f / den;
        float v[7];
        #pragma unroll
        for (int c = 0; c < 7; ++c) v[c] = a[c] * inv + b2[c];
        float mx = v[0];
        #pragma unroll
        for (int c = 1; c < 7; ++c) mx = fmaxf(mx, v[c]);
        float s7 = 0.f;
        #pragma unroll
        for (int c = 0; c < 7; ++c) s7 += __expf(v[c] - mx);
        float lg = mx + __logf(s7);
        float* op = &out[(size_t)node * 7];
        #pragma unroll
        for (int c = 0; c < 7; ++c) op[c] = v[c] - lg;
    }
}

// ---------------- launcher ----------------
extern "C" void kernel_launch(void* const* d_in, const int* in_sizes, int n_in,
                              void* d_out, int out_size, void* d_ws, size_t ws_size,
                              hipStream_t stream)
{
    (void)n_in; (void)out_size; (void)ws_size;
    const float* x      = (const float*)d_in[0];
    const int*   ei     = (const int*)d_in[1];
    const int    E      = in_sizes[1] / 2;
    const float* W1     = (const float*)d_in[2];
    const float* asrc1  = (const float*)d_in[3];
    const float* adst1  = (const float*)d_in[4];
    const float* b1     = (const float*)d_in[5];
    const float* W2     = (const float*)d_in[6];
    const float* asrc2  = (const float*)d_in[7];
    const float* adst2  = (const float*)d_in[8];
    const float* b2     = (const float*)d_in[9];
    float* out = (float*)d_out;

    char* p = (char*)d_ws;
    auto alloc = [&](size_t bytes) -> void* {
        void* r = (void*)p;
        p += (bytes + 255) & ~(size_t)255;
        return r;
    };
    int*    deg     = (int*)alloc((size_t)NN * 4);
    int*    row_off = (int*)alloc((size_t)(NN + 1) * 4);
    int*    rank    = (int*)alloc((size_t)E * 4);
    int*    bsum    = (int*)alloc((size_t)NB_SCAN * 4);
    int*    csr     = (int*)alloc((size_t)E * 4);
    __bf16* w1h     = (__bf16*)alloc((size_t)64 * KPAD * 2);
    __bf16* w1l     = (__bf16*)alloc((size_t)64 * KPAD * 2);
    __bf16* Hb      = (__bf16*)alloc((size_t)NN * 64 * 2);   // 128B rows
    float*  x2      = (float*)alloc((size_t)NN * 64 * 4);
    __bf16* h2b     = (__bf16*)alloc((size_t)NN * 8 * 2);    // 16B records
    float*  ad2     = (float*)alloc((size_t)NN * 4);

    const int* src = ei;
    const int* dst = ei + E;

    k_prep   <<<64 + NB_SCAN, 256, 0, stream>>>(W1, w1h, w1l, deg);
    k_rank   <<<(E + 1023) / 1024, 256, 0, stream>>>(dst, deg, rank, E);
    k_scan1  <<<NB_SCAN, 256, 0, stream>>>(deg, bsum);
    k_scan3  <<<NB_SCAN, 256, 0, stream>>>(deg, bsum, row_off);
    k_scatter<<<(E + 1023) / 1024, 256, 0, stream>>>(src, dst, rank, row_off, csr, E);
    k_gemm1  <<<(NN + 63) / 64, 256, 0, stream>>>(x, w1h, w1l, Hb);
    k_layer1 <<<L1B, 256, 0, stream>>>(asrc1, adst1, Hb, row_off, csr, b1, x2);
    k_gemm2  <<<(NN + 255) / 256, 256, 0, stream>>>(x2, W2, asrc2, adst2, h2b, ad2);
    k_layer2 <<<(NN + 31) / 32, 256, 0, stream>>>(ad2, h2b, row_off, csr, b2, out);
}